// Round 4
// baseline (8224.088 us; speedup 1.0000x reference)
//
#include <hip/hip_runtime.h>
#include <stdint.h>

// Problem constants
#define Sn 64
#define Un 10
#define Tn 160
#define Fn 80
#define Bn 640      // S*U
#define Hn 768
#define Pn 256
#define En 256
#define G4H 3072
#define NBLK 240    // 3 layers x 5 mt (M=128) x 16 ct
#define SAP 104     // padded sA row stride (shorts)

using short8  = __attribute__((ext_vector_type(8))) short;
using short4v = __attribute__((ext_vector_type(4))) short;
using floatx4 = __attribute__((ext_vector_type(4))) float;

__device__ __forceinline__ short f2bf(float f){
    unsigned u = __builtin_bit_cast(unsigned, f);
    u += 0x7fffu + ((u >> 16) & 1u);
    return (short)(u >> 16);
}
__device__ __forceinline__ float bf2f(short s){
    return __builtin_bit_cast(float, ((unsigned)(unsigned short)s) << 16);
}
__device__ __forceinline__ float sigm(float x){ return 1.f / (1.f + __expf(-x)); }
__device__ __forceinline__ float tanh_(float x){
    float e = __expf(-2.f * fmaxf(x, -40.f));
    return (1.f - e) / (1.f + e);
}
// keep a loaded value materialized here (prevents load sinking past this point)
__device__ __forceinline__ void pin8(const short8& v){
    asm volatile("" :: "v"(__builtin_bit_cast(floatx4, v)));
}

// ---------------- prep: bias sums + Wih0 -> B0 tail columns -----------------
__global__ void k_prep(const float* __restrict__ Wih0,
                       const float* bi0, const float* bh0,
                       const float* bi1, const float* bh1,
                       const float* bi2, const float* bh2,
                       short* __restrict__ B0, float* __restrict__ bias){
    int i = blockIdx.x * 256 + threadIdx.x;
    const int W0 = G4H * 96;
    if (i < W0){
        int g = i / 96, c = i % 96;
        B0[(size_t)g * 864 + 768 + c] = (c < Fn) ? f2bf(Wih0[(size_t)g * Fn + c]) : (short)0;
    } else if (i < W0 + 3 * G4H){
        int j = i - W0; int l = j / G4H, g = j % G4H;
        const float* a = (l == 0) ? bi0 : (l == 1) ? bi1 : bi2;
        const float* b = (l == 0) ? bh0 : (l == 1) ? bh1 : bh2;
        bias[j] = a[g] + b[g];
    }
}

// ---------------- init: zero hidden (bf16) and c (fp32) ---------------------
__global__ void k_init(short* __restrict__ hidden, float* __restrict__ c){
    int i = blockIdx.x * 256 + threadIdx.x;
    int stride = gridDim.x * 256;
    const int NH = 3 * 2 * Bn * Hn;   // shorts
    const int NC = 3 * Bn * Hn;       // floats
    for (int j = i; j < NH; j += stride) hidden[j] = 0;
    for (int j = i; j < NC; j += stride) c[j] = 0.f;
}

// ---------------- fold: out[m][n] = sum_p A[m][p] * Whr[p][n]  (K=256) ------
__global__ void k_fold(const float* __restrict__ A, const float* __restrict__ Whr,
                       short* __restrict__ out, int ldout, int coloff, int Mtiles){
    int mt = blockIdx.x % Mtiles, nt = blockIdx.x / Mtiles;
    int lane = threadIdx.x & 63;
    int ln = lane & 15, lq = lane >> 4;
    floatx4 acc = {0.f, 0.f, 0.f, 0.f};
    const float* ap = A + (size_t)(mt * 16 + ln) * 256 + lq * 8;
    const float* bp = Whr + (size_t)(lq * 8) * 768 + nt * 16 + ln;
    for (int p0 = 0; p0 < 256; p0 += 32){
        short8 af, bf;
        #pragma unroll
        for (int j = 0; j < 8; ++j) af[j] = f2bf(ap[p0 + j]);
        #pragma unroll
        for (int j = 0; j < 8; ++j) bf[j] = f2bf(bp[(size_t)(p0 + j) * 768]);
        acc = __builtin_amdgcn_mfma_f32_16x16x32_bf16(af, bf, acc, 0, 0, 0);
    }
    #pragma unroll
    for (int r = 0; r < 4; ++r){
        int row = mt * 16 + lq * 4 + r, col = nt * 16 + ln;
        out[(size_t)row * ldout + coloff + col] = f2bf(acc[r]);
    }
}

// ---------------- per-wavefront step kernel, M=128 --------------------------
// 240 blocks x 256 thr, 1 block/CU. layer = bid%3, r2 = bid/3: mt = r2>>4
// (128 rows), ct = r2&15 (48 H-dims). Wave wg handles gate wg (i,f,g,o) for
// all 128 rows (acc[8][3]). hidden[layer][parity][b][j] bf16.
// K layout: L0: [hid_prev(768) | x(96 pad)]; L1/2: [hid_below(768)|hid_prev(768)].
// LDS: sA (26.6 KB) and sEx (100.3 KB) OVERLAY (disjoint lifetimes).
// Prefetch: depth-1 ping-pong B-fragment + A registers, pinned with empty asm
// + sched_barrier so the compiler cannot sink the loads to their use.
__global__ __launch_bounds__(256, 1) void k_step(const float* __restrict__ x,
        const short* __restrict__ B0, const short* __restrict__ B1,
        const short* __restrict__ B2, const float* __restrict__ bias,
        short* __restrict__ hidden, float* __restrict__ c, int w){
    __shared__ __align__(16) char smem[4 * 128 * 49 * 4];   // 100,352 B
    short* sA  = (short*)smem;          // [128][SAP] = 26,624 B (head alias)
    float* sEx = (float*)smem;          // [4][128][49]

    const int tid = threadIdx.x, lane = tid & 63, wg = tid >> 6;
    const int bid = blockIdx.x;
    const int layer = bid % 3;
    const int t = w - layer;
    if (t < 0 || t >= Tn) return;
    const int r2 = bid / 3;
    const int mt = r2 >> 4, ct = r2 & 15;
    const int m0 = mt * 128, j0 = ct * 48;
    const short* Bl = (layer == 0) ? B0 : (layer == 1) ? B1 : B2;
    const int KTOT = (layer == 0) ? 864 : 1536;
    const int NCH = KTOT / 96;
    const int ln = lane & 15, lq = lane >> 4;
    const int rr2 = tid >> 1, ch2 = (tid & 1) * 48, cb = (tid & 1) * 24;
    const int pp = (w + 1) & 1;   // parity written by previous wavefront

    // B fragment row pointers (per nt), stride KTOT
    const short* brow0 = Bl + (size_t)(wg * Hn + j0 +  0 + ln) * KTOT + lq * 8;
    const short* brow1 = Bl + (size_t)(wg * Hn + j0 + 16 + ln) * KTOT + lq * 8;
    const short* brow2 = Bl + (size_t)(wg * Hn + j0 + 32 + ln) * KTOT + lq * 8;

    // A sources: chunks 0..7 = (layer==0 ? own h_prev : below h_prev);
    // chunks 8..15 (layer>=1) = own h_prev; layer 0 chunk 8 = x tail.
    const short* srcA = (layer == 0) ? hidden + (size_t)pp * Bn * Hn
                       : hidden + (size_t)((layer - 1) * 2 + pp) * Bn * Hn;
    const short* srcH = hidden + (size_t)(layer * 2 + pp) * Bn * Hn;

    floatx4 acc[8][3];
    #pragma unroll
    for (int nt = 0; nt < 3; ++nt){
        float bv = bias[layer * G4H + wg * Hn + j0 + nt * 16 + ln];
        #pragma unroll
        for (int m8 = 0; m8 < 8; ++m8){
            acc[m8][nt][0] = bv; acc[m8][nt][1] = bv;
            acc[m8][nt][2] = bv; acc[m8][nt][3] = bv;
        }
    }

    short8 aR[6];                 // A prefetch registers (chunk ch+1)
    short8 bA[3][3], bB[3][3];    // B prefetch ping-pong [ks][nt]

    auto loadB = [&](int chn, short8 (&bL)[3][3]){
        const int kk = chn * 96;
        #pragma unroll
        for (int ks = 0; ks < 3; ++ks){
            bL[ks][0] = *(const short8*)&brow0[kk + ks * 32];
            bL[ks][1] = *(const short8*)&brow1[kk + ks * 32];
            bL[ks][2] = *(const short8*)&brow2[kk + ks * 32];
        }
    };
    auto loadA = [&](int chn){
        if (layer == 0 && chn == 8){
            const float* xr = x + ((size_t)(m0 + rr2) * Tn + t) * Fn;
            #pragma unroll
            for (int ii = 0; ii < 6; ++ii){
                int f = ch2 + ii * 8;
                short8 v = {0,0,0,0,0,0,0,0};
                if (f < Fn){
                    float4 a = *(const float4*)(xr + f);
                    float4 b = *(const float4*)(xr + f + 4);
                    v[0]=f2bf(a.x); v[1]=f2bf(a.y); v[2]=f2bf(a.z); v[3]=f2bf(a.w);
                    v[4]=f2bf(b.x); v[5]=f2bf(b.y); v[6]=f2bf(b.z); v[7]=f2bf(b.w);
                }
                aR[ii] = v;
            }
        } else {
            const short* src = (chn < 8) ? srcA : srcH;
            int jj = (chn < 8) ? chn * 96 : chn * 96 - 768;
            const short* srow = src + (size_t)(m0 + rr2) * Hn + jj + ch2;
            #pragma unroll
            for (int ii = 0; ii < 6; ++ii) aR[ii] = *(const short8*)&srow[ii * 8];
        }
    };
    auto pinAll = [&](short8 (&bL)[3][3]){
        #pragma unroll
        for (int ks = 0; ks < 3; ++ks)
            #pragma unroll
            for (int nt = 0; nt < 3; ++nt) pin8(bL[ks][nt]);
        #pragma unroll
        for (int ii = 0; ii < 6; ++ii) pin8(aR[ii]);
        __builtin_amdgcn_sched_barrier(0);
    };
    auto writeA = [&](){
        #pragma unroll
        for (int ii = 0; ii < 6; ++ii)
            *(short8*)&sA[rr2 * SAP + ch2 + ii * 8] = aR[ii];
    };
    auto mfmaCh = [&](short8 (&bU)[3][3]){
        #pragma unroll
        for (int ks = 0; ks < 3; ++ks){
            short8 afr[8];
            #pragma unroll
            for (int m8 = 0; m8 < 8; ++m8)
                afr[m8] = *(const short8*)&sA[(m8 * 16 + ln) * SAP + ks * 32 + lq * 8];
            #pragma unroll
            for (int m8 = 0; m8 < 8; ++m8)
                #pragma unroll
                for (int nt = 0; nt < 3; ++nt)
                    acc[m8][nt] = __builtin_amdgcn_mfma_f32_16x16x32_bf16(afr[m8], bU[ks][nt], acc[m8][nt], 0, 0, 0);
        }
    };
    auto chunk = [&](int ch, short8 (&bU)[3][3], short8 (&bL)[3][3]){
        const int chn = ch + 1;
        const bool has = chn < NCH;
        if (has){ loadB(chn, bL); loadA(chn); pinAll(bL); } // issue + pin early
        mfmaCh(bU);
        __syncthreads();            // all waves done reading sA(ch)
        if (has){
            writeA();               // aR landed during MFMA phase
            __syncthreads();        // sA(ch+1) visible
        }
    };

    // prologue: stage chunk 0
    loadB(0, bA);
    loadA(0);
    writeA();
    __syncthreads();

    for (int ch = 0; ch < NCH; ch += 2){
        chunk(ch, bA, bB);
        if (ch + 1 < NCH) chunk(ch + 1, bB, bA);
    }

    // ---- sA lifetime over; overlay region becomes sEx ----
    // exchange gates via LDS (wave wg holds gate wg for 128 rows x 48 cols)
    #pragma unroll
    for (int m8 = 0; m8 < 8; ++m8)
        #pragma unroll
        for (int nt = 0; nt < 3; ++nt)
            #pragma unroll
            for (int r = 0; r < 4; ++r)
                sEx[((size_t)wg * 128 + m8 * 16 + lq * 4 + r) * 49 + nt * 16 + ln] = acc[m8][nt][r];
    __syncthreads();
    // cell update: thread -> row rr2, cells cb..cb+23 (global c fp32)
    {
        float* cp = c + ((size_t)layer * Bn + (m0 + rr2)) * Hn + j0 + cb;
        short hb[24];
        #pragma unroll
        for (int ii = 0; ii < 24; ++ii){
            int cc_ = cb + ii;
            float gi = sEx[(0 * 128 + rr2) * 49 + cc_];
            float gf = sEx[(1 * 128 + rr2) * 49 + cc_];
            float gg = sEx[(2 * 128 + rr2) * 49 + cc_];
            float go = sEx[(3 * 128 + rr2) * 49 + cc_];
            float cv = sigm(gf) * cp[ii] + sigm(gi) * tanh_(gg);
            cp[ii] = cv;
            hb[ii] = f2bf(sigm(go) * tanh_(cv));
        }
        short* hp = hidden + ((size_t)(layer * 2 + (w & 1)) * Bn + (m0 + rr2)) * Hn + j0 + cb;
        #pragma unroll
        for (int q = 0; q < 3; ++q){
            short8 v;
            #pragma unroll
            for (int k = 0; k < 8; ++k) v[k] = hb[q * 8 + k];
            *(short8*)&hp[q * 8] = v;
        }
    }
}

// ---------------- final: emb = normalize(relu(hidden2_last @ Wf^T + b)) -----
__global__ void k_final(const short* __restrict__ h2, const short* __restrict__ Wf,
                        const float* __restrict__ blin, float* __restrict__ out){
    __shared__ __align__(16) short sH[768];
    __shared__ float sW[4];
    int b = blockIdx.x, e = threadIdx.x;
    if (e < 96) *(short8*)&sH[e * 8] = *(const short8*)&h2[(size_t)b * 768 + e * 8];
    __syncthreads();
    float acc = blin[e];
    const short* wr = Wf + (size_t)e * 768;
    for (int j = 0; j < 768; j += 8){
        short8 hv = *(const short8*)&sH[j];
        short8 wv = *(const short8*)&wr[j];
        #pragma unroll
        for (int k = 0; k < 8; ++k) acc += bf2f(hv[k]) * bf2f(wv[k]);
    }
    float v = fmaxf(acc, 0.f);
    float s = v * v;
    #pragma unroll
    for (int off = 32; off >= 1; off >>= 1) s += __shfl_down(s, off);
    if ((e & 63) == 0) sW[e >> 6] = s;
    __syncthreads();
    float tot = sW[0] + sW[1] + sW[2] + sW[3];
    float scale = 1.f / fmaxf(sqrtf(tot), 1e-12f);
    out[(size_t)b * 256 + e] = v * scale;
}

// ---------------- host launcher ---------------------------------------------
extern "C" void kernel_launch(void* const* d_in, const int* in_sizes, int n_in,
                              void* d_out, int out_size, void* d_ws, size_t ws_size,
                              hipStream_t stream){
    const float* x    = (const float*)d_in[0];
    const float* Wih0 = (const float*)d_in[1];
    const float* Whh0 = (const float*)d_in[2];
    const float* bi0  = (const float*)d_in[3];
    const float* bh0  = (const float*)d_in[4];
    const float* Whr0 = (const float*)d_in[5];
    const float* Wih1 = (const float*)d_in[6];
    const float* Whh1 = (const float*)d_in[7];
    const float* bi1  = (const float*)d_in[8];
    const float* bh1  = (const float*)d_in[9];
    const float* Whr1 = (const float*)d_in[10];
    const float* Wih2 = (const float*)d_in[11];
    const float* Whh2 = (const float*)d_in[12];
    const float* bi2  = (const float*)d_in[13];
    const float* bh2  = (const float*)d_in[14];
    const float* Whr2 = (const float*)d_in[15];
    const float* Wlin = (const float*)d_in[16];
    const float* blin = (const float*)d_in[17];

    char* wp = (char*)d_ws;
    size_t off = 0;
    auto alloc = [&](size_t bytes) -> char* {
        char* p = wp + off; off += (bytes + 255) & ~(size_t)255; return p;
    };
    short* B0   = (short*)alloc((size_t)G4H * 864 * 2);
    short* B1   = (short*)alloc((size_t)G4H * 1536 * 2);
    short* B2   = (short*)alloc((size_t)G4H * 1536 * 2);
    short* Wf   = (short*)alloc((size_t)256 * 768 * 2);
    float* bias = (float*)alloc((size_t)3 * G4H * 4);
    short* hid  = (short*)alloc((size_t)3 * 2 * Bn * Hn * 2);
    float* cst  = (float*)alloc((size_t)3 * Bn * Hn * 4);

    hipLaunchKernelGGL(k_prep, dim3(1188), dim3(256), 0, stream,
                       Wih0, bi0, bh0, bi1, bh1, bi2, bh2, B0, bias);
    hipLaunchKernelGGL(k_init, dim3(1024), dim3(256), 0, stream, hid, cst);
    // folds: R_l = Whh_l @ Whr_l ; U_l = Wih_l @ Whr_{l-1} ; Wf = Wlin @ Whr2
    hipLaunchKernelGGL(k_fold, dim3(192 * 48), dim3(64), 0, stream, Whh0, Whr0, B0, 864, 0, 192);
    hipLaunchKernelGGL(k_fold, dim3(192 * 48), dim3(64), 0, stream, Wih1, Whr0, B1, 1536, 0, 192);
    hipLaunchKernelGGL(k_fold, dim3(192 * 48), dim3(64), 0, stream, Whh1, Whr1, B1, 1536, 768, 192);
    hipLaunchKernelGGL(k_fold, dim3(192 * 48), dim3(64), 0, stream, Wih2, Whr1, B2, 1536, 0, 192);
    hipLaunchKernelGGL(k_fold, dim3(192 * 48), dim3(64), 0, stream, Whh2, Whr2, B2, 1536, 768, 192);
    hipLaunchKernelGGL(k_fold, dim3(16 * 48), dim3(64), 0, stream, Wlin, Whr2, Wf, 768, 0, 16);

    // stream-ordered wavefront pipeline: one launch per wavefront
    for (int w = 0; w < 162; ++w)
        hipLaunchKernelGGL(k_step, dim3(NBLK), dim3(256), 0, stream,
                           x, B0, B1, B2, bias, hid, cst, w);

    const short* h2 = hid + (size_t)5 * Bn * Hn;   // hidden[2][parity 1]
    hipLaunchKernelGGL(k_final, dim3(Bn), dim3(256), 0, stream, h2, Wf, blin, (float*)d_out);
}

// Round 5
// 8140.715 us; speedup vs baseline: 1.0102x; 1.0102x over previous
//
#include <hip/hip_runtime.h>
#include <stdint.h>

// Problem constants
#define Sn 64
#define Un 10
#define Tn 160
#define Fn 80
#define Bn 640      // S*U
#define Hn 768
#define Pn 256
#define En 256
#define G4H 3072
#define NBLK 480
#define NSTEP 162   // Tn + 2 layer skew

using short8  = __attribute__((ext_vector_type(8))) short;
using short4v = __attribute__((ext_vector_type(4))) short;
using floatx4 = __attribute__((ext_vector_type(4))) float;

__device__ __forceinline__ short f2bf(float f){
    unsigned u = __builtin_bit_cast(unsigned, f);
    u += 0x7fffu + ((u >> 16) & 1u);
    return (short)(u >> 16);
}
__device__ __forceinline__ float bf2f(short s){
    return __builtin_bit_cast(float, ((unsigned)(unsigned short)s) << 16);
}
__device__ __forceinline__ float sigm(float x){ return 1.f / (1.f + __expf(-x)); }
__device__ __forceinline__ float tanh_(float x){
    float e = __expf(-2.f * fmaxf(x, -40.f));
    return (1.f - e) / (1.f + e);
}

// LLC-coherent 16B load / 8B store (bypass L1+L2: sc0 sc1). Caller MUST
// execute s_waitcnt vmcnt(0) before using loaded values / signaling stores.
__device__ __forceinline__ short8 llc_load16(const short* p){
    short8 v;
    asm volatile("global_load_dwordx4 %0, %1, off sc0 sc1"
                 : "=v"(v) : "v"(p) : "memory");
    return v;
}
__device__ __forceinline__ void llc_store8(short* p, uint2 v){
    asm volatile("global_store_dwordx2 %0, %1, off sc0 sc1"
                 :: "v"(p), "v"(v) : "memory");
}
__device__ __forceinline__ void wait_vm0(){
    asm volatile("s_waitcnt vmcnt(0)" ::: "memory");
}

// ---------------- prep: bias sums + Wih0 -> B0 tail columns -----------------
__global__ void k_prep(const float* __restrict__ Wih0,
                       const float* bi0, const float* bh0,
                       const float* bi1, const float* bh1,
                       const float* bi2, const float* bh2,
                       short* __restrict__ B0, float* __restrict__ bias){
    int i = blockIdx.x * 256 + threadIdx.x;
    const int W0 = G4H * 96;
    if (i < W0){
        int g = i / 96, c = i % 96;
        B0[(size_t)g * 864 + 768 + c] = (c < Fn) ? f2bf(Wih0[(size_t)g * Fn + c]) : (short)0;
    } else if (i < W0 + 3 * G4H){
        int j = i - W0; int l = j / G4H, g = j % G4H;
        const float* a = (l == 0) ? bi0 : (l == 1) ? bi1 : bi2;
        const float* b = (l == 0) ? bh0 : (l == 1) ? bh1 : bh2;
        bias[j] = a[g] + b[g];
    }
}

// ---------------- init: zero hidden (bf16) and barrier vars -----------------
__global__ void k_init(short* __restrict__ hidden, unsigned* __restrict__ bar){
    int i = blockIdx.x * 256 + threadIdx.x;
    int stride = gridDim.x * 256;
    const int NH = 3 * 2 * Bn * Hn;   // shorts
    for (int j = i; j < NH; j += stride) hidden[j] = 0;
    for (int j = i; j < 1024; j += stride) bar[j] = 0u;
}

// ---------------- fold: out[m][n] = sum_p A[m][p] * Whr[p][n]  (K=256) ------
__global__ void k_fold(const float* __restrict__ A, const float* __restrict__ Whr,
                       short* __restrict__ out, int ldout, int coloff, int Mtiles){
    int mt = blockIdx.x % Mtiles, nt = blockIdx.x / Mtiles;
    int lane = threadIdx.x & 63;
    int ln = lane & 15, lq = lane >> 4;
    floatx4 acc = {0.f, 0.f, 0.f, 0.f};
    const float* ap = A + (size_t)(mt * 16 + ln) * 256 + lq * 8;
    const float* bp = Whr + (size_t)(lq * 8) * 768 + nt * 16 + ln;
    for (int p0 = 0; p0 < 256; p0 += 32){
        short8 af, bf;
        #pragma unroll
        for (int j = 0; j < 8; ++j) af[j] = f2bf(ap[p0 + j]);
        #pragma unroll
        for (int j = 0; j < 8; ++j) bf[j] = f2bf(bp[(size_t)(p0 + j) * 768]);
        acc = __builtin_amdgcn_mfma_f32_16x16x32_bf16(af, bf, acc, 0, 0, 0);
    }
    #pragma unroll
    for (int r = 0; r < 4; ++r){
        int row = mt * 16 + lq * 4 + r, col = nt * 16 + ln;
        out[(size_t)row * ldout + coloff + col] = f2bf(acc[r]);
    }
}

// ---------------- grid barrier: RELAXED-only atomics (no cache fences) ------
// No acquire/release: per-XCD L2 is never invalidated, so read-only weights
// stay L2-resident across steps. h coherence is handled per-instruction
// (sc0 sc1 LLC ops) by the callers. bar: subc[8] padded x32, mast=bar[256],
// flag=bar[257]. 480 blocks, 60 per sub-counter.
__device__ __forceinline__ void gbar(int w, unsigned* __restrict__ bar){
    __syncthreads();
    if (threadIdx.x == 0){
        unsigned tgt = (unsigned)(w + 1);
        unsigned* subc = bar + ((blockIdx.x & 7) << 5);
        unsigned old = __hip_atomic_fetch_add(subc, 1u,
                           __ATOMIC_RELAXED, __HIP_MEMORY_SCOPE_AGENT);
        if (old + 1u == 60u * tgt){
            unsigned mo = __hip_atomic_fetch_add(bar + 256, 1u,
                           __ATOMIC_RELAXED, __HIP_MEMORY_SCOPE_AGENT);
            if (mo + 1u == 8u * tgt)
                __hip_atomic_store(bar + 257, tgt,
                           __ATOMIC_RELAXED, __HIP_MEMORY_SCOPE_AGENT);
        }
        while (__hip_atomic_load(bar + 257, __ATOMIC_RELAXED,
                                 __HIP_MEMORY_SCOPE_AGENT) < tgt)
            __builtin_amdgcn_s_sleep(1);
    }
    __syncthreads();
}

// ---------------- persistent step kernel ------------------------------------
// 480 blocks x 256 thr, all co-resident (LDS 62.4 KB -> 2 blocks/CU).
// layer = bid%3, r2 = bid/3: mt = r2>>4 (64 rows), ct = r2&15 (48 H-dims).
// Wave wg handles gate wg (i,f,g,o). hidden[layer][parity][b][j] bf16,
// accessed ONLY via LLC-coherent sc0sc1 ops inside this kernel.
// Weights/bias/x: normal cached loads (read-only -> never stale).
// c-state: registers (12 cells/thread) across all 162 steps.
__global__ __launch_bounds__(256, 2) void k_loop(const float* __restrict__ x,
        const short* __restrict__ B0, const short* __restrict__ B1,
        const short* __restrict__ B2, const float* __restrict__ bias,
        short* __restrict__ hidden, unsigned* __restrict__ bar){
    __shared__ __align__(16) short sA[64 * 96];
    __shared__ float sEx[4 * 64 * 49];

    const int tid = threadIdx.x, lane = tid & 63, wg = tid >> 6;
    const int bid = blockIdx.x;
    const int layer = bid % 3;
    const int r2 = bid / 3;
    const int mt = r2 >> 4, ct = r2 & 15;
    const int m0 = mt * 64, j0 = ct * 48;
    const short* Bl = (layer == 0) ? B0 : (layer == 1) ? B1 : B2;
    const int KTOT = (layer == 0) ? 864 : 1536;
    const int NCH = KTOT / 96;
    const int ln = lane & 15, lq = lane >> 4;
    const int rr = tid >> 2, cg24 = (tid & 3) * 24, cb = (tid & 3) * 12;

    float bv3[3];
    #pragma unroll
    for (int nt = 0; nt < 3; ++nt)
        bv3[nt] = bias[layer * G4H + wg * Hn + j0 + nt * 16 + ln];
    float creg[12];
    #pragma unroll
    for (int ii = 0; ii < 12; ++ii) creg[ii] = 0.f;

    for (int w = 0; w < NSTEP; ++w){
        const int t = w - layer;
        if (t >= 0 && t < Tn){
            const int pp = (w + 1) & 1;   // parity written by previous step

            floatx4 acc[4][3];
            #pragma unroll
            for (int nt = 0; nt < 3; ++nt){
                float bv = bv3[nt];
                #pragma unroll
                for (int m4 = 0; m4 < 4; ++m4){
                    acc[m4][nt][0] = bv; acc[m4][nt][1] = bv;
                    acc[m4][nt][2] = bv; acc[m4][nt][3] = bv;
                }
            }

            for (int ch = 0; ch < NCH; ++ch){
                int k0 = ch * 96;
                if (ch) __syncthreads();   // protect sA from prev iter's reads
                if (layer == 0 && ch == 8){
                    const float* xr = x + ((size_t)(m0 + rr) * Tn + t) * Fn;
                    #pragma unroll
                    for (int ii = 0; ii < 3; ++ii){
                        int f = cg24 + ii * 8;
                        short8 v = {0,0,0,0,0,0,0,0};
                        if (f < Fn){
                            float4 a = *(const float4*)(xr + f);
                            float4 b = *(const float4*)(xr + f + 4);
                            v[0]=f2bf(a.x); v[1]=f2bf(a.y); v[2]=f2bf(a.z); v[3]=f2bf(a.w);
                            v[4]=f2bf(b.x); v[5]=f2bf(b.y); v[6]=f2bf(b.z); v[7]=f2bf(b.w);
                        }
                        *(short8*)&sA[rr * 96 + f] = v;
                    }
                } else {
                    const short* src; int jj;
                    if (layer == 0){ src = hidden + (size_t)pp * Bn * Hn; jj = k0; }
                    else if (k0 < 768){ src = hidden + (size_t)((layer - 1) * 2 + pp) * Bn * Hn; jj = k0; }
                    else { src = hidden + (size_t)(layer * 2 + pp) * Bn * Hn; jj = k0 - 768; }
                    const short* srow = src + (size_t)(m0 + rr) * Hn + jj + cg24;
                    short8 a0 = llc_load16(&srow[0]);
                    short8 a1 = llc_load16(&srow[8]);
                    short8 a2 = llc_load16(&srow[16]);
                    wait_vm0();             // asm loads are not scoreboarded
                    *(short8*)&sA[rr * 96 + cg24 +  0] = a0;
                    *(short8*)&sA[rr * 96 + cg24 +  8] = a1;
                    *(short8*)&sA[rr * 96 + cg24 + 16] = a2;
                }
                __syncthreads();
                #pragma unroll
                for (int ks = 0; ks < 3; ++ks){
                    int kk = k0 + ks * 32 + lq * 8;
                    short8 bfr[3], afr[4];
                    #pragma unroll
                    for (int nt = 0; nt < 3; ++nt)
                        bfr[nt] = *(const short8*)&Bl[(size_t)(wg * Hn + j0 + nt * 16 + ln) * KTOT + kk];
                    #pragma unroll
                    for (int m4 = 0; m4 < 4; ++m4)
                        afr[m4] = *(const short8*)&sA[(m4 * 16 + ln) * 96 + ks * 32 + lq * 8];
                    #pragma unroll
                    for (int m4 = 0; m4 < 4; ++m4)
                        #pragma unroll
                        for (int nt = 0; nt < 3; ++nt)
                            acc[m4][nt] = __builtin_amdgcn_mfma_f32_16x16x32_bf16(afr[m4], bfr[nt], acc[m4][nt], 0, 0, 0);
                }
            }
            __syncthreads();
            // exchange gates via LDS (wave wg holds gate wg, 64 rows x 48 cols)
            #pragma unroll
            for (int m4 = 0; m4 < 4; ++m4)
                #pragma unroll
                for (int nt = 0; nt < 3; ++nt)
                    #pragma unroll
                    for (int r = 0; r < 4; ++r)
                        sEx[(wg * 64 + m4 * 16 + lq * 4 + r) * 49 + nt * 16 + ln] = acc[m4][nt][r];
            __syncthreads();
            // cell update: thread -> row rr, cells cb..cb+11; c in registers
            {
                short hb[12];
                #pragma unroll
                for (int ii = 0; ii < 12; ++ii){
                    int cc_ = cb + ii;
                    float gi = sEx[(0 * 64 + rr) * 49 + cc_];
                    float gf = sEx[(1 * 64 + rr) * 49 + cc_];
                    float gg = sEx[(2 * 64 + rr) * 49 + cc_];
                    float go = sEx[(3 * 64 + rr) * 49 + cc_];
                    float cv = sigm(gf) * creg[ii] + sigm(gi) * tanh_(gg);
                    creg[ii] = cv;
                    hb[ii] = f2bf(sigm(go) * tanh_(cv));
                }
                short* hp = hidden + ((size_t)(layer * 2 + (w & 1)) * Bn + (m0 + rr)) * Hn + j0 + cb;
                #pragma unroll
                for (int q = 0; q < 3; ++q){
                    uint2 v;
                    v.x = (unsigned)(unsigned short)hb[q * 4 + 0] |
                          ((unsigned)(unsigned short)hb[q * 4 + 1] << 16);
                    v.y = (unsigned)(unsigned short)hb[q * 4 + 2] |
                          ((unsigned)(unsigned short)hb[q * 4 + 3] << 16);
                    llc_store8(&hp[q * 4], v);
                }
                wait_vm0();   // h stores at LLC before barrier arrival
            }
        }
        gbar(w, bar);
    }
}

// ---------------- final: emb = normalize(relu(hidden2_last @ Wf^T + b)) -----
__global__ void k_final(const short* __restrict__ h2, const short* __restrict__ Wf,
                        const float* __restrict__ blin, float* __restrict__ out){
    __shared__ __align__(16) short sH[768];
    __shared__ float sW[4];
    int b = blockIdx.x, e = threadIdx.x;
    if (e < 96) *(short8*)&sH[e * 8] = *(const short8*)&h2[(size_t)b * 768 + e * 8];
    __syncthreads();
    float acc = blin[e];
    const short* wr = Wf + (size_t)e * 768;
    for (int j = 0; j < 768; j += 8){
        short8 hv = *(const short8*)&sH[j];
        short8 wv = *(const short8*)&wr[j];
        #pragma unroll
        for (int k = 0; k < 8; ++k) acc += bf2f(hv[k]) * bf2f(wv[k]);
    }
    float v = fmaxf(acc, 0.f);
    float s = v * v;
    #pragma unroll
    for (int off = 32; off >= 1; off >>= 1) s += __shfl_down(s, off);
    if ((e & 63) == 0) sW[e >> 6] = s;
    __syncthreads();
    float tot = sW[0] + sW[1] + sW[2] + sW[3];
    float scale = 1.f / fmaxf(sqrtf(tot), 1e-12f);
    out[(size_t)b * 256 + e] = v * scale;
}

// ---------------- host launcher ---------------------------------------------
extern "C" void kernel_launch(void* const* d_in, const int* in_sizes, int n_in,
                              void* d_out, int out_size, void* d_ws, size_t ws_size,
                              hipStream_t stream){
    const float* x    = (const float*)d_in[0];
    const float* Wih0 = (const float*)d_in[1];
    const float* Whh0 = (const float*)d_in[2];
    const float* bi0  = (const float*)d_in[3];
    const float* bh0  = (const float*)d_in[4];
    const float* Whr0 = (const float*)d_in[5];
    const float* Wih1 = (const float*)d_in[6];
    const float* Whh1 = (const float*)d_in[7];
    const float* bi1  = (const float*)d_in[8];
    const float* bh1  = (const float*)d_in[9];
    const float* Whr1 = (const float*)d_in[10];
    const float* Wih2 = (const float*)d_in[11];
    const float* Whh2 = (const float*)d_in[12];
    const float* bi2  = (const float*)d_in[13];
    const float* bh2  = (const float*)d_in[14];
    const float* Whr2 = (const float*)d_in[15];
    const float* Wlin = (const float*)d_in[16];
    const float* blin = (const float*)d_in[17];

    char* wp = (char*)d_ws;
    size_t off = 0;
    auto alloc = [&](size_t bytes) -> char* {
        char* p = wp + off; off += (bytes + 255) & ~(size_t)255; return p;
    };
    short*    B0   = (short*)alloc((size_t)G4H * 864 * 2);
    short*    B1   = (short*)alloc((size_t)G4H * 1536 * 2);
    short*    B2   = (short*)alloc((size_t)G4H * 1536 * 2);
    short*    Wf   = (short*)alloc((size_t)256 * 768 * 2);
    float*    bias = (float*)alloc((size_t)3 * G4H * 4);
    short*    hid  = (short*)alloc((size_t)3 * 2 * Bn * Hn * 2);
    unsigned* bar  = (unsigned*)alloc((size_t)1024 * 4);

    hipLaunchKernelGGL(k_prep, dim3(1188), dim3(256), 0, stream,
                       Wih0, bi0, bh0, bi1, bh1, bi2, bh2, B0, bias);
    hipLaunchKernelGGL(k_init, dim3(1024), dim3(256), 0, stream, hid, bar);
    // folds: R_l = Whh_l @ Whr_l ; U_l = Wih_l @ Whr_{l-1} ; Wf = Wlin @ Whr2
    hipLaunchKernelGGL(k_fold, dim3(192 * 48), dim3(64), 0, stream, Whh0, Whr0, B0, 864, 0, 192);
    hipLaunchKernelGGL(k_fold, dim3(192 * 48), dim3(64), 0, stream, Wih1, Whr0, B1, 1536, 0, 192);
    hipLaunchKernelGGL(k_fold, dim3(192 * 48), dim3(64), 0, stream, Whh1, Whr1, B1, 1536, 768, 192);
    hipLaunchKernelGGL(k_fold, dim3(192 * 48), dim3(64), 0, stream, Wih2, Whr1, B2, 1536, 0, 192);
    hipLaunchKernelGGL(k_fold, dim3(192 * 48), dim3(64), 0, stream, Whh2, Whr2, B2, 1536, 768, 192);
    hipLaunchKernelGGL(k_fold, dim3(16 * 48), dim3(64), 0, stream, Wlin, Whr2, Wf, 768, 0, 16);

    // persistent wavefront pipeline: ONE launch, relaxed grid barrier
    hipLaunchKernelGGL(k_loop, dim3(NBLK), dim3(256), 0, stream,
                       x, B0, B1, B2, bias, hid, bar);

    const short* h2 = hid + (size_t)5 * Bn * Hn;   // hidden[2][parity 1]
    hipLaunchKernelGGL(k_final, dim3(Bn), dim3(256), 0, stream, h2, Wf, blin, (float*)d_out);
}

// Round 7
// 7298.564 us; speedup vs baseline: 1.1268x; 1.1154x over previous
//
#include <hip/hip_runtime.h>
#include <stdint.h>

// Problem constants
#define Sn 64
#define Un 10
#define Tn 160
#define Fn 80
#define Bn 640      // S*U
#define Hn 768
#define Pn 256
#define En 256
#define G4H 3072
#define NBLK 480

using short8  = __attribute__((ext_vector_type(8))) short;
using short4v = __attribute__((ext_vector_type(4))) short;
using floatx4 = __attribute__((ext_vector_type(4))) float;

__device__ __forceinline__ short f2bf(float f){
    unsigned u = __builtin_bit_cast(unsigned, f);
    u += 0x7fffu + ((u >> 16) & 1u);
    return (short)(u >> 16);
}
__device__ __forceinline__ float bf2f(short s){
    return __builtin_bit_cast(float, ((unsigned)(unsigned short)s) << 16);
}
__device__ __forceinline__ float sigm(float x){ return 1.f / (1.f + __expf(-x)); }
__device__ __forceinline__ float tanh_(float x){
    float e = __expf(-2.f * fmaxf(x, -40.f));
    return (1.f - e) / (1.f + e);
}

// async global->LDS DMA, 16B per lane. lds base wave-uniform; HW adds lane*16.
__device__ __forceinline__ void gll(const short* g, short* l){
    __builtin_amdgcn_global_load_lds(
        (const __attribute__((address_space(1))) unsigned int*)(const void*)g,
        (__attribute__((address_space(3))) unsigned int*)(void*)l, 16, 0, 0);
}
#define VMW(N) asm volatile("s_waitcnt vmcnt(" #N ")" ::: "memory")

// ---------------- prep: bias sums + Wih0 -> B0 tail columns -----------------
__global__ void k_prep(const float* __restrict__ Wih0,
                       const float* bi0, const float* bh0,
                       const float* bi1, const float* bh1,
                       const float* bi2, const float* bh2,
                       short* __restrict__ B0, float* __restrict__ bias){
    int i = blockIdx.x * 256 + threadIdx.x;
    const int W0 = G4H * 96;
    if (i < W0){
        int g = i / 96, c = i % 96;
        B0[(size_t)g * 864 + 768 + c] = (c < Fn) ? f2bf(Wih0[(size_t)g * Fn + c]) : (short)0;
    } else if (i < W0 + 3 * G4H){
        int j = i - W0; int l = j / G4H, g = j % G4H;
        const float* a = (l == 0) ? bi0 : (l == 1) ? bi1 : bi2;
        const float* b = (l == 0) ? bh0 : (l == 1) ? bh1 : bh2;
        bias[j] = a[g] + b[g];
    }
}

// ---------------- init: zero hidden (bf16) and c (fp32) ---------------------
__global__ void k_init(short* __restrict__ hidden, float* __restrict__ c){
    int i = blockIdx.x * 256 + threadIdx.x;
    int stride = gridDim.x * 256;
    const int NH = 3 * 2 * Bn * Hn;
    const int NC = 3 * Bn * Hn;
    for (int j = i; j < NH; j += stride) hidden[j] = 0;
    for (int j = i; j < NC; j += stride) c[j] = 0.f;
}

// ---------------- fold: out[m][n] = sum_p A[m][p] * Whr[p][n]  (K=256) ------
__global__ void k_fold(const float* __restrict__ A, const float* __restrict__ Whr,
                       short* __restrict__ out, int ldout, int coloff, int Mtiles){
    int mt = blockIdx.x % Mtiles, nt = blockIdx.x / Mtiles;
    int lane = threadIdx.x & 63;
    int ln = lane & 15, lq = lane >> 4;
    floatx4 acc = {0.f, 0.f, 0.f, 0.f};
    const float* ap = A + (size_t)(mt * 16 + ln) * 256 + lq * 8;
    const float* bp = Whr + (size_t)(lq * 8) * 768 + nt * 16 + ln;
    for (int p0 = 0; p0 < 256; p0 += 32){
        short8 af, bf;
        #pragma unroll
        for (int j = 0; j < 8; ++j) af[j] = f2bf(ap[p0 + j]);
        #pragma unroll
        for (int j = 0; j < 8; ++j) bf[j] = f2bf(bp[(size_t)(p0 + j) * 768]);
        acc = __builtin_amdgcn_mfma_f32_16x16x32_bf16(af, bf, acc, 0, 0, 0);
    }
    #pragma unroll
    for (int r = 0; r < 4; ++r){
        int row = mt * 16 + lq * 4 + r, col = nt * 16 + ln;
        out[(size_t)row * ldout + coloff + col] = f2bf(acc[r]);
    }
}

// ---------------- per-wavefront step kernel: DMA-pipelined ------------------
// 480 blocks x 256 thr (2 blocks/CU). layer=bid%3, r2=bid/3: mt=r2>>4 (64
// rows), ct=r2&15 (48 H-dims). Wave wg = gate wg.
// B fragments: global_load_lds into per-wave-private 3-slot ring (slot=ks),
//   issued 2 ks-stages ahead, guarded by counted vmcnt only (no barrier).
// A tile: global_load_lds into 64x128-short swizzled double buffer, FULL
//   coverage: 4 waves x 4 gll x 64 lanes = 1024 units = 64 rows x 16 units.
//   (Round-6 bug: 3 gll/wave only covered rows 0-47.) Units 12-15 hold
//   never-read padding (bounded overread absorbed by cst buffer).
// Steady-chunk vmcnt ledger (per wave, in-order retirement):
//   enter {Bs,Bs+1}=6; +A(ch+1)=10; ks0:+3=13,w(10); ks1:+3=13,w(10);
//   ks2:+3=13,w(6) -> A retired before barrier, exit {Bs+3,Bs+4}=6.
__global__ __launch_bounds__(256, 4) void k_step(const float* __restrict__ x,
        const short* __restrict__ B0, const short* __restrict__ B1,
        const short* __restrict__ B2, const float* __restrict__ bias,
        short* __restrict__ hidden, float* __restrict__ c, int w){
    __shared__ __align__(16) short sB[3 * 6144];    // 36,864 B  B ring
    __shared__ __align__(16) short sA2[2 * 8192];   // 32,768 B  A dbuf 64x(16 units)
    float* sEx = (float*)sB;                        // overlay [4][32][49] fp32

    const int tid = threadIdx.x, lane = tid & 63, wg = tid >> 6;
    const int bid = blockIdx.x;
    const int layer = bid % 3;
    const int t = w - layer;
    if (t < 0 || t >= Tn) return;
    const int r2 = bid / 3;
    const int mt = r2 >> 4, ct = r2 & 15;
    const int m0 = mt * 64, j0 = ct * 48;
    const short* Bl = (layer == 0) ? B0 : (layer == 1) ? B1 : B2;
    const int KTOT = (layer == 0) ? 864 : 1536;
    const int NCH = KTOT / 96;
    const int ln = lane & 15, lq = lane >> 4;
    const int swz = ln & 7;
    const int rr = tid >> 2, cg24 = (tid & 3) * 24;
    const int pp = (w + 1) & 1;

    // B global per-lane row bases (fragment row = wg*768+j0+nt*16+ln, +lq*8)
    const short* bgl[3];
    #pragma unroll
    for (int nt = 0; nt < 3; ++nt)
        bgl[nt] = Bl + (size_t)(wg * Hn + j0 + nt * 16 + ln) * KTOT + lq * 8;

    // A DMA lane mapping: unit u=(wg*4+j)*64+lane -> row=u>>4, cu=u&15;
    // LDS unit u holds global column-unit (cu ^ (row&7))  [source-side swizzle]
    int aoff[4];
    #pragma unroll
    for (int j = 0; j < 4; ++j){
        int u = (wg * 4 + j) * 64 + lane;
        int rowA = u >> 4, cuA = u & 15;
        aoff[j] = rowA * Hn + ((cuA ^ (rowA & 7)) * 8);
    }

    const short* srcA = (layer == 0) ? hidden + (size_t)pp * Bn * Hn
                       : hidden + (size_t)((layer - 1) * 2 + pp) * Bn * Hn;
    const short* srcH = hidden + (size_t)(layer * 2 + pp) * Bn * Hn;

    auto issueB = [&](int s, int slot){
        #pragma unroll
        for (int nt = 0; nt < 3; ++nt)
            gll(bgl[nt] + s * 32, &sB[slot * 6144 + (wg * 3 + nt) * 512]);
    };
    auto issueA = [&](int chn){
        const short* src; int jj;
        if (layer == 0 || chn < 8){ src = srcA; jj = chn * 96; }
        else { src = srcH; jj = chn * 96 - 768; }
        const short* gb = src + (size_t)m0 * Hn + jj;
        #pragma unroll
        for (int j = 0; j < 4; ++j)
            gll(gb + aoff[j], &sA2[(chn & 1) * 8192 + (wg * 4 + j) * 512]);
    };

    floatx4 acc[4][3];
    #pragma unroll
    for (int nt = 0; nt < 3; ++nt){
        float bv = bias[layer * G4H + wg * Hn + j0 + nt * 16 + ln];
        #pragma unroll
        for (int m4 = 0; m4 < 4; ++m4){
            acc[m4][nt][0] = bv; acc[m4][nt][1] = bv;
            acc[m4][nt][2] = bv; acc[m4][nt][3] = bv;
        }
    }

#define KSP(ks, WAITN, ISSUE)                                                   \
    {                                                                           \
        ISSUE;                                                                  \
        VMW(WAITN);                                                             \
        short8 afr[4], bfr[3];                                                  \
        _Pragma("unroll")                                                       \
        for (int nt = 0; nt < 3; ++nt)                                          \
            bfr[nt] = *(const short8*)&sB[(ks) * 6144 + (wg * 3 + nt) * 512 + lane * 8]; \
        _Pragma("unroll")                                                       \
        for (int m4 = 0; m4 < 4; ++m4)                                          \
            afr[m4] = *(const short8*)&sA2[abuf * 8192 + (m4 * 16 + ln) * 128 + (((ks) * 4 + lq) ^ swz) * 8]; \
        _Pragma("unroll")                                                       \
        for (int m4 = 0; m4 < 4; ++m4)                                          \
            _Pragma("unroll")                                                   \
            for (int nt = 0; nt < 3; ++nt)                                      \
                acc[m4][nt] = __builtin_amdgcn_mfma_f32_16x16x32_bf16(afr[m4], bfr[nt], acc[m4][nt], 0, 0, 0); \
    }

    // prologue: A(0), B stage0 -> slot0, stage1 -> slot1.
    // VMW(6) retires bias+A0 (leaves exactly the 2 B stages), robust to the
    // bias-load instruction count.
    issueA(0);
    issueB(0, 0);
    issueB(1, 1);
    VMW(6);
    __builtin_amdgcn_s_barrier();

    const int NSTEADY = (layer == 0) ? 7 : (NCH - 1);
    for (int ch = 0; ch < NSTEADY; ++ch){
        const int s0 = 3 * ch;
        const int abuf = ch & 1;
        issueA(ch + 1);
        KSP(0, 10, issueB(s0 + 2, 2));
        KSP(1, 10, issueB(s0 + 3, 0));
        KSP(2, 6,  issueB(s0 + 4, 1));
        __builtin_amdgcn_s_barrier();
    }
    if (layer == 0){
        // chunk 7: no A-issue variant (chunk 8 is x, not DMA)
        {
            const int s0 = 21, abuf = 1;
            KSP(0, 6, issueB(s0 + 2, 2));
            KSP(1, 6, issueB(s0 + 3, 0));
            KSP(2, 6, issueB(s0 + 4, 1));
            __builtin_amdgcn_s_barrier();
        }
        // x-insert into buffer 0 (chunk 8), swizzled like the DMA layout
        {
            const float* xr = x + ((size_t)(m0 + rr) * Tn + t) * Fn;
            #pragma unroll
            for (int ii = 0; ii < 3; ++ii){
                int f = cg24 + ii * 8;
                short8 v = {0,0,0,0,0,0,0,0};
                if (f < Fn){
                    float4 a = *(const float4*)(xr + f);
                    float4 b = *(const float4*)(xr + f + 4);
                    v[0]=f2bf(a.x); v[1]=f2bf(a.y); v[2]=f2bf(a.z); v[3]=f2bf(a.w);
                    v[4]=f2bf(b.x); v[5]=f2bf(b.y); v[6]=f2bf(b.z); v[7]=f2bf(b.w);
                }
                int unit = rr * 16 + (((cg24 >> 3) + ii) ^ (rr & 7));
                *(short8*)&sA2[unit * 8] = v;
            }
            __syncthreads();   // drains vmcnt too — harmless once per step
        }
        // chunk 8: last variant
        {
            const int s0 = 24, abuf = 0;
            KSP(0, 6, issueB(s0 + 2, 2));
            KSP(1, 3, (void)0);
            KSP(2, 0, (void)0);
            __syncthreads();
        }
    } else {
        // chunk NCH-1: last variant
        {
            const int s0 = 3 * (NCH - 1);
            const int abuf = (NCH - 1) & 1;
            KSP(0, 6, issueB(s0 + 2, 2));
            KSP(1, 3, (void)0);
            KSP(2, 0, (void)0);
            __syncthreads();
        }
    }
#undef KSP

    // ---- epilogue: 2-phase gate exchange (sEx overlays sB) ----
    #pragma unroll
    for (int p = 0; p < 2; ++p){
        if (p) __syncthreads();
        #pragma unroll
        for (int mm = 0; mm < 2; ++mm){
            int m4 = p * 2 + mm;
            #pragma unroll
            for (int nt = 0; nt < 3; ++nt)
                #pragma unroll
                for (int r = 0; r < 4; ++r)
                    sEx[(wg * 32 + mm * 16 + lq * 4 + r) * 49 + nt * 16 + ln] = acc[m4][nt][r];
        }
        __syncthreads();
        {
            int r32 = tid >> 3, cbp = (tid & 7) * 6;
            int row = p * 32 + r32;
            float* cp = c + ((size_t)layer * Bn + (m0 + row)) * Hn + j0 + cbp;
            short hb[6];
            #pragma unroll
            for (int ii = 0; ii < 6; ++ii){
                int cc_ = cbp + ii;
                float gi = sEx[(0 * 32 + r32) * 49 + cc_];
                float gf = sEx[(1 * 32 + r32) * 49 + cc_];
                float gg = sEx[(2 * 32 + r32) * 49 + cc_];
                float go = sEx[(3 * 32 + r32) * 49 + cc_];
                float cv = sigm(gf) * cp[ii] + sigm(gi) * tanh_(gg);
                cp[ii] = cv;
                hb[ii] = f2bf(sigm(go) * tanh_(cv));
            }
            short* hp = hidden + ((size_t)(layer * 2 + (w & 1)) * Bn + (m0 + row)) * Hn + j0 + cbp;
            #pragma unroll
            for (int q = 0; q < 3; ++q){
                unsigned v = (unsigned)(unsigned short)hb[q * 2] |
                             ((unsigned)(unsigned short)hb[q * 2 + 1] << 16);
                *(unsigned*)&hp[q * 2] = v;
            }
        }
    }
}

// ---------------- final: emb = normalize(relu(hidden2_last @ Wf^T + b)) -----
__global__ void k_final(const short* __restrict__ h2, const short* __restrict__ Wf,
                        const float* __restrict__ blin, float* __restrict__ out){
    __shared__ __align__(16) short sH[768];
    __shared__ float sW[4];
    int b = blockIdx.x, e = threadIdx.x;
    if (e < 96) *(short8*)&sH[e * 8] = *(const short8*)&h2[(size_t)b * 768 + e * 8];
    __syncthreads();
    float acc = blin[e];
    const short* wr = Wf + (size_t)e * 768;
    for (int j = 0; j < 768; j += 8){
        short8 hv = *(const short8*)&sH[j];
        short8 wv = *(const short8*)&wr[j];
        #pragma unroll
        for (int k = 0; k < 8; ++k) acc += bf2f(hv[k]) * bf2f(wv[k]);
    }
    float v = fmaxf(acc, 0.f);
    float s = v * v;
    #pragma unroll
    for (int off = 32; off >= 1; off >>= 1) s += __shfl_down(s, off);
    if ((e & 63) == 0) sW[e >> 6] = s;
    __syncthreads();
    float tot = sW[0] + sW[1] + sW[2] + sW[3];
    float scale = 1.f / fmaxf(sqrtf(tot), 1e-12f);
    out[(size_t)b * 256 + e] = v * scale;
}

// ---------------- host launcher ---------------------------------------------
extern "C" void kernel_launch(void* const* d_in, const int* in_sizes, int n_in,
                              void* d_out, int out_size, void* d_ws, size_t ws_size,
                              hipStream_t stream){
    const float* x    = (const float*)d_in[0];
    const float* Wih0 = (const float*)d_in[1];
    const float* Whh0 = (const float*)d_in[2];
    const float* bi0  = (const float*)d_in[3];
    const float* bh0  = (const float*)d_in[4];
    const float* Whr0 = (const float*)d_in[5];
    const float* Wih1 = (const float*)d_in[6];
    const float* Whh1 = (const float*)d_in[7];
    const float* bi1  = (const float*)d_in[8];
    const float* bh1  = (const float*)d_in[9];
    const float* Whr1 = (const float*)d_in[10];
    const float* Wih2 = (const float*)d_in[11];
    const float* Whh2 = (const float*)d_in[12];
    const float* bi2  = (const float*)d_in[13];
    const float* bh2  = (const float*)d_in[14];
    const float* Whr2 = (const float*)d_in[15];
    const float* Wlin = (const float*)d_in[16];
    const float* blin = (const float*)d_in[17];

    char* wp = (char*)d_ws;
    size_t off = 0;
    auto alloc = [&](size_t bytes) -> char* {
        char* p = wp + off; off += (bytes + 255) & ~(size_t)255; return p;
    };
    short* B0   = (short*)alloc((size_t)G4H * 864 * 2);
    short* B1   = (short*)alloc((size_t)G4H * 1536 * 2);
    short* B2   = (short*)alloc((size_t)G4H * 1536 * 2);
    short* Wf   = (short*)alloc((size_t)256 * 768 * 2);
    float* bias = (float*)alloc((size_t)3 * G4H * 4);
    short* hid  = (short*)alloc((size_t)3 * 2 * Bn * Hn * 2);
    float* cst  = (float*)alloc((size_t)3 * Bn * Hn * 4);   // also absorbs hid overread

    hipLaunchKernelGGL(k_prep, dim3(1188), dim3(256), 0, stream,
                       Wih0, bi0, bh0, bi1, bh1, bi2, bh2, B0, bias);
    hipLaunchKernelGGL(k_init, dim3(1024), dim3(256), 0, stream, hid, cst);
    hipLaunchKernelGGL(k_fold, dim3(192 * 48), dim3(64), 0, stream, Whh0, Whr0, B0, 864, 0, 192);
    hipLaunchKernelGGL(k_fold, dim3(192 * 48), dim3(64), 0, stream, Wih1, Whr0, B1, 1536, 0, 192);
    hipLaunchKernelGGL(k_fold, dim3(192 * 48), dim3(64), 0, stream, Whh1, Whr1, B1, 1536, 768, 192);
    hipLaunchKernelGGL(k_fold, dim3(192 * 48), dim3(64), 0, stream, Wih2, Whr1, B2, 1536, 0, 192);
    hipLaunchKernelGGL(k_fold, dim3(192 * 48), dim3(64), 0, stream, Whh2, Whr2, B2, 1536, 768, 192);
    hipLaunchKernelGGL(k_fold, dim3(16 * 48), dim3(64), 0, stream, Wlin, Whr2, Wf, 768, 0, 16);

    for (int w = 0; w < 162; ++w)
        hipLaunchKernelGGL(k_step, dim3(NBLK), dim3(256), 0, stream,
                           x, B0, B1, B2, bias, hid, cst, w);

    const short* h2 = hid + (size_t)5 * Bn * Hn;
    hipLaunchKernelGGL(k_final, dim3(Bn), dim3(256), 0, stream, h2, Wf, blin, (float*)d_out);
}

// Round 8
// 7157.977 us; speedup vs baseline: 1.1489x; 1.0196x over previous
//
#include <hip/hip_runtime.h>
#include <stdint.h>

// Problem constants
#define Sn 64
#define Un 10
#define Tn 160
#define Fn 80
#define Bn 640      // S*U
#define Hn 768
#define Pn 256
#define En 256
#define G4H 3072
#define NBLK 480

using short8  = __attribute__((ext_vector_type(8))) short;
using short4v = __attribute__((ext_vector_type(4))) short;
using floatx4 = __attribute__((ext_vector_type(4))) float;

__device__ __forceinline__ short f2bf(float f){
    unsigned u = __builtin_bit_cast(unsigned, f);
    u += 0x7fffu + ((u >> 16) & 1u);
    return (short)(u >> 16);
}
__device__ __forceinline__ float bf2f(short s){
    return __builtin_bit_cast(float, ((unsigned)(unsigned short)s) << 16);
}
__device__ __forceinline__ float sigm(float x){ return 1.f / (1.f + __expf(-x)); }
__device__ __forceinline__ float tanh_(float x){
    float e = __expf(-2.f * fmaxf(x, -40.f));
    return (1.f - e) / (1.f + e);
}

// async global->LDS DMA, 16B per lane. lds base wave-uniform; HW adds lane*16.
__device__ __forceinline__ void gll(const short* g, short* l){
    __builtin_amdgcn_global_load_lds(
        (const __attribute__((address_space(1))) unsigned int*)(const void*)g,
        (__attribute__((address_space(3))) unsigned int*)(void*)l, 16, 0, 0);
}
#define VMW(N) asm volatile("s_waitcnt vmcnt(" #N ")" ::: "memory")
#define LGKM0  asm volatile("s_waitcnt lgkmcnt(0)" ::: "memory")

// ---------------- prep: bias sums + Wih0 -> B0 tail columns -----------------
__global__ void k_prep(const float* __restrict__ Wih0,
                       const float* bi0, const float* bh0,
                       const float* bi1, const float* bh1,
                       const float* bi2, const float* bh2,
                       short* __restrict__ B0, float* __restrict__ bias){
    int i = blockIdx.x * 256 + threadIdx.x;
    const int W0 = G4H * 96;
    if (i < W0){
        int g = i / 96, c = i % 96;
        B0[(size_t)g * 864 + 768 + c] = (c < Fn) ? f2bf(Wih0[(size_t)g * Fn + c]) : (short)0;
    } else if (i < W0 + 3 * G4H){
        int j = i - W0; int l = j / G4H, g = j % G4H;
        const float* a = (l == 0) ? bi0 : (l == 1) ? bi1 : bi2;
        const float* b = (l == 0) ? bh0 : (l == 1) ? bh1 : bh2;
        bias[j] = a[g] + b[g];
    }
}

// ---------------- init: zero hidden (bf16) and c (fp32) ---------------------
__global__ void k_init(short* __restrict__ hidden, float* __restrict__ c){
    int i = blockIdx.x * 256 + threadIdx.x;
    int stride = gridDim.x * 256;
    const int NH = 3 * 2 * Bn * Hn;
    const int NC = 3 * Bn * Hn;
    for (int j = i; j < NH; j += stride) hidden[j] = 0;
    for (int j = i; j < NC; j += stride) c[j] = 0.f;
}

// ---------------- fold: out[m][n] = sum_p A[m][p] * Whr[p][n]  (K=256) ------
__global__ void k_fold(const float* __restrict__ A, const float* __restrict__ Whr,
                       short* __restrict__ out, int ldout, int coloff, int Mtiles){
    int mt = blockIdx.x % Mtiles, nt = blockIdx.x / Mtiles;
    int lane = threadIdx.x & 63;
    int ln = lane & 15, lq = lane >> 4;
    floatx4 acc = {0.f, 0.f, 0.f, 0.f};
    const float* ap = A + (size_t)(mt * 16 + ln) * 256 + lq * 8;
    const float* bp = Whr + (size_t)(lq * 8) * 768 + nt * 16 + ln;
    for (int p0 = 0; p0 < 256; p0 += 32){
        short8 af, bf;
        #pragma unroll
        for (int j = 0; j < 8; ++j) af[j] = f2bf(ap[p0 + j]);
        #pragma unroll
        for (int j = 0; j < 8; ++j) bf[j] = f2bf(bp[(size_t)(p0 + j) * 768]);
        acc = __builtin_amdgcn_mfma_f32_16x16x32_bf16(af, bf, acc, 0, 0, 0);
    }
    #pragma unroll
    for (int r = 0; r < 4; ++r){
        int row = mt * 16 + lq * 4 + r, col = nt * 16 + ln;
        out[(size_t)row * ldout + coloff + col] = f2bf(acc[r]);
    }
}

// ---------------- per-wavefront step kernel: deep DMA pipeline --------------
// 480 blocks x 256 thr (2 blocks/CU). layer=bid%3, r2=bid/3: mt=r2>>4 (64
// rows), ct=r2&15 (48 H-dims). Wave wg = gate wg.
// B: 4-slot ring (slot = stage&3); stage p+4 issued at phase p, consumed at
//   phase p+4 -> uniform 4-phase prefetch distance. Phase order:
//   VMW -> ds_read -> lgkmcnt(0) -> issue (same slot just read) -> MFMA.
// A: 64 rows x 12 units (16B), rotate swizzle: LDS(row,kc') holds global
//   chunk kcg=(kc'-row)%12. Double buffer, issued 1 chunk ahead (3 phases).
// Steady ledger (per wave, in-order): entering chunk = 9 [B+1,B+2,B+3];
//   +A(3)=12; ph0 VMW(12) [B(s0) retired at prev chunk-end], issue -> 15;
//   ph1 VMW(12) retires B(s0+1); ph2 VMW(12); end VMW(9) retires B(s0+3)+A.
__global__ __launch_bounds__(256, 4) void k_step(const float* __restrict__ x,
        const short* __restrict__ B0, const short* __restrict__ B1,
        const short* __restrict__ B2, const float* __restrict__ bias,
        short* __restrict__ hidden, float* __restrict__ c, int w){
    __shared__ __align__(16) short sB[4 * 6144];    // 49,152 B  B ring (4 slots)
    __shared__ __align__(16) short sAr[2 * 6144];   // 24,576 B  A dbuf 64x12 units
    float* sEx = (float*)sB;                        // overlay [4][32][49] fp32

    const int tid = threadIdx.x, lane = tid & 63, wg = tid >> 6;
    const int bid = blockIdx.x;
    const int layer = bid % 3;
    const int t = w - layer;
    if (t < 0 || t >= Tn) return;
    const int r2 = bid / 3;
    const int mt = r2 >> 4, ct = r2 & 15;
    const int m0 = mt * 64, j0 = ct * 48;
    const short* Bl = (layer == 0) ? B0 : (layer == 1) ? B1 : B2;
    const int KTOT = (layer == 0) ? 864 : 1536;
    const int ln = lane & 15, lq = lane >> 4;
    const int rr = tid >> 2;
    const int pp = (w + 1) & 1;

    // B global per-lane row bases (fragment row = wg*768+j0+nt*16+ln, +lq*8)
    const short* bgl[3];
    #pragma unroll
    for (int nt = 0; nt < 3; ++nt)
        bgl[nt] = Bl + (size_t)(wg * Hn + j0 + nt * 16 + ln) * KTOT + lq * 8;

    // A DMA lane mapping: unit u=(wg*3+j)*64+lane covers 64 rows x 12 units;
    // LDS unit (row,kc') <- global chunk kcg=(kc'-row)%12 (rotate swizzle).
    int aoffA[3];
    #pragma unroll
    for (int j = 0; j < 3; ++j){
        int u = (wg * 3 + j) * 64 + lane;
        int row = u / 12, kcp = u % 12;
        int kcg = kcp - (row % 12); if (kcg < 0) kcg += 12;
        aoffA[j] = row * Hn + kcg * 8;
    }
    // afr read: row = m4*16+ln; kc' = (row + ks*4+lq) % 12
    int prem[4];
    #pragma unroll
    for (int m4 = 0; m4 < 4; ++m4) prem[m4] = (m4 * 16 + ln) % 12;

    const short* srcA = (layer == 0) ? hidden + (size_t)pp * Bn * Hn
                       : hidden + (size_t)((layer - 1) * 2 + pp) * Bn * Hn;
    const short* srcH = hidden + (size_t)(layer * 2 + pp) * Bn * Hn;

    auto issueB = [&](int s){
        #pragma unroll
        for (int nt = 0; nt < 3; ++nt)
            gll(bgl[nt] + s * 32, &sB[(s & 3) * 6144 + (wg * 3 + nt) * 512]);
    };
    auto issueA = [&](int chn){
        const short* src; int jj;
        if (layer == 0 || chn < 8){ src = srcA; jj = chn * 96; }
        else { src = srcH; jj = chn * 96 - 768; }
        const short* gb = src + (size_t)m0 * Hn + jj;
        #pragma unroll
        for (int j = 0; j < 3; ++j)
            gll(gb + aoffA[j], &sAr[(chn & 1) * 6144 + (wg * 3 + j) * 512]);
    };

    floatx4 acc[4][3];
    #pragma unroll
    for (int nt = 0; nt < 3; ++nt){
        float bv = bias[layer * G4H + wg * Hn + j0 + nt * 16 + ln];
        #pragma unroll
        for (int m4 = 0; m4 < 4; ++m4){
            acc[m4][nt][0] = bv; acc[m4][nt][1] = bv;
            acc[m4][nt][2] = bv; acc[m4][nt][3] = bv;
        }
    }

// phase: VMW -> reads -> LGKM0 (pin read<DMA-issue) -> issue -> MFMA
#define PH(ks_, slot_, WAITN, ISSUE)                                            \
    {                                                                           \
        VMW(WAITN);                                                             \
        short8 bfr[3], afr[4];                                                  \
        _Pragma("unroll")                                                       \
        for (int nt = 0; nt < 3; ++nt)                                          \
            bfr[nt] = *(const short8*)&sB[(slot_) * 6144 + (wg * 3 + nt) * 512 + lane * 8]; \
        const int ksl_ = (ks_) * 4 + lq;                                        \
        _Pragma("unroll")                                                       \
        for (int m4 = 0; m4 < 4; ++m4){                                         \
            int idx = prem[m4] + ksl_; if (idx >= 12) idx -= 12;                \
            afr[m4] = *(const short8*)&sAr[abuf * 6144 + ((m4 * 16 + ln) * 12 + idx) * 8]; \
        }                                                                       \
        LGKM0;                                                                  \
        ISSUE;                                                                  \
        _Pragma("unroll")                                                       \
        for (int m4 = 0; m4 < 4; ++m4)                                          \
            _Pragma("unroll")                                                   \
            for (int nt = 0; nt < 3; ++nt)                                      \
                acc[m4][nt] = __builtin_amdgcn_mfma_f32_16x16x32_bf16(afr[m4], bfr[nt], acc[m4][nt], 0, 0, 0); \
    }

    // prologue: A(0) [3], B stages 0-3 [12]; VMW(12) retires A(0); barrier.
    issueA(0);
    issueB(0); issueB(1); issueB(2); issueB(3);
    VMW(12);
    __builtin_amdgcn_s_barrier();

    const int NST = (layer == 0) ? 7 : 14;   // steady chunks
    for (int ch = 0; ch < NST; ++ch){
        const int s0 = 3 * ch;
        const int abuf = ch & 1;
        issueA(ch + 1);
        PH(0, (s0 + 0) & 3, 12, issueB(s0 + 4));
        PH(1, (s0 + 1) & 3, 12, issueB(s0 + 5));
        PH(2, (s0 + 2) & 3, 12, issueB(s0 + 6));
        VMW(9);                      // retires B(s0+3) + A(ch+1)
        __builtin_amdgcn_s_barrier();
    }
    if (layer == 0){
        // chunk 7 (abuf=1): no A-issue (chunk 8 is x); B stages end at 26
        {
            const int abuf = 1;
            PH(0, 1, 9, issueB(25));
            PH(1, 2, 9, issueB(26));
            PH(2, 3, 9, (void)0);
            __builtin_amdgcn_s_barrier();
        }
        // x-insert into A buf 0 with rotate layout
        {
            const float* xr = x + ((size_t)(m0 + rr) * Tn + t) * Fn;
            int q3 = (tid & 3) * 3;
            #pragma unroll
            for (int ii = 0; ii < 3; ++ii){
                int kcg = q3 + ii;          // global chunk 0..11
                int f = kcg * 8;
                short8 v = {0,0,0,0,0,0,0,0};
                if (f < Fn){
                    float4 a = *(const float4*)(xr + f);
                    float4 b = *(const float4*)(xr + f + 4);
                    v[0]=f2bf(a.x); v[1]=f2bf(a.y); v[2]=f2bf(a.z); v[3]=f2bf(a.w);
                    v[4]=f2bf(b.x); v[5]=f2bf(b.y); v[6]=f2bf(b.z); v[7]=f2bf(b.w);
                }
                int kcp = kcg + (rr % 12); if (kcp >= 12) kcp -= 12;
                *(short8*)&sAr[(rr * 12 + kcp) * 8] = v;
            }
            LGKM0;
            __builtin_amdgcn_s_barrier();
        }
        // chunk 8 (abuf=0): tail, entering [B24,B25,B26]=9
        {
            const int abuf = 0;
            PH(0, 0, 6, (void)0);
            PH(1, 1, 3, (void)0);
            PH(2, 2, 0, (void)0);
            __builtin_amdgcn_s_barrier();
        }
    } else {
        // chunk 14 (abuf=0): A(15) + partial B issue (stages end at 47)
        {
            const int abuf = 0;
            issueA(15);
            PH(0, 2, 12, issueB(46));
            PH(1, 3, 12, issueB(47));
            PH(2, 0, 12, (void)0);
            VMW(6);                  // retires B45 + A(15)
            __builtin_amdgcn_s_barrier();
        }
        // chunk 15 (abuf=1): tail, entering [B46,B47]=6
        {
            const int abuf = 1;
            PH(0, 1, 6, (void)0);
            PH(1, 2, 3, (void)0);
            PH(2, 3, 0, (void)0);
            __builtin_amdgcn_s_barrier();
        }
    }
#undef PH

    // ---- epilogue: 2-phase gate exchange (sEx overlays sB; all DMA drained) ----
    #pragma unroll
    for (int p = 0; p < 2; ++p){
        if (p) __syncthreads();
        #pragma unroll
        for (int mm = 0; mm < 2; ++mm){
            int m4 = p * 2 + mm;
            #pragma unroll
            for (int nt = 0; nt < 3; ++nt)
                #pragma unroll
                for (int r = 0; r < 4; ++r)
                    sEx[(wg * 32 + mm * 16 + lq * 4 + r) * 49 + nt * 16 + ln] = acc[m4][nt][r];
        }
        __syncthreads();
        {
            int r32 = tid >> 3, cbp = (tid & 7) * 6;
            int row = p * 32 + r32;
            float* cp = c + ((size_t)layer * Bn + (m0 + row)) * Hn + j0 + cbp;
            short hb[6];
            #pragma unroll
            for (int ii = 0; ii < 6; ++ii){
                int cc_ = cbp + ii;
                float gi = sEx[(0 * 32 + r32) * 49 + cc_];
                float gf = sEx[(1 * 32 + r32) * 49 + cc_];
                float gg = sEx[(2 * 32 + r32) * 49 + cc_];
                float go = sEx[(3 * 32 + r32) * 49 + cc_];
                float cv = sigm(gf) * cp[ii] + sigm(gi) * tanh_(gg);
                cp[ii] = cv;
                hb[ii] = f2bf(sigm(go) * tanh_(cv));
            }
            short* hp = hidden + ((size_t)(layer * 2 + (w & 1)) * Bn + (m0 + row)) * Hn + j0 + cbp;
            #pragma unroll
            for (int q = 0; q < 3; ++q){
                unsigned v = (unsigned)(unsigned short)hb[q * 2] |
                             ((unsigned)(unsigned short)hb[q * 2 + 1] << 16);
                *(unsigned*)&hp[q * 2] = v;
            }
        }
    }
}

// ---------------- final: emb = normalize(relu(hidden2_last @ Wf^T + b)) -----
__global__ void k_final(const short* __restrict__ h2, const short* __restrict__ Wf,
                        const float* __restrict__ blin, float* __restrict__ out){
    __shared__ __align__(16) short sH[768];
    __shared__ float sW[4];
    int b = blockIdx.x, e = threadIdx.x;
    if (e < 96) *(short8*)&sH[e * 8] = *(const short8*)&h2[(size_t)b * 768 + e * 8];
    __syncthreads();
    float acc = blin[e];
    const short* wr = Wf + (size_t)e * 768;
    for (int j = 0; j < 768; j += 8){
        short8 hv = *(const short8*)&sH[j];
        short8 wv = *(const short8*)&wr[j];
        #pragma unroll
        for (int k = 0; k < 8; ++k) acc += bf2f(hv[k]) * bf2f(wv[k]);
    }
    float v = fmaxf(acc, 0.f);
    float s = v * v;
    #pragma unroll
    for (int off = 32; off >= 1; off >>= 1) s += __shfl_down(s, off);
    if ((e & 63) == 0) sW[e >> 6] = s;
    __syncthreads();
    float tot = sW[0] + sW[1] + sW[2] + sW[3];
    float scale = 1.f / fmaxf(sqrtf(tot), 1e-12f);
    out[(size_t)b * 256 + e] = v * scale;
}

// ---------------- host launcher ---------------------------------------------
extern "C" void kernel_launch(void* const* d_in, const int* in_sizes, int n_in,
                              void* d_out, int out_size, void* d_ws, size_t ws_size,
                              hipStream_t stream){
    const float* x    = (const float*)d_in[0];
    const float* Wih0 = (const float*)d_in[1];
    const float* Whh0 = (const float*)d_in[2];
    const float* bi0  = (const float*)d_in[3];
    const float* bh0  = (const float*)d_in[4];
    const float* Whr0 = (const float*)d_in[5];
    const float* Wih1 = (const float*)d_in[6];
    const float* Whh1 = (const float*)d_in[7];
    const float* bi1  = (const float*)d_in[8];
    const float* bh1  = (const float*)d_in[9];
    const float* Whr1 = (const float*)d_in[10];
    const float* Wih2 = (const float*)d_in[11];
    const float* Whh2 = (const float*)d_in[12];
    const float* bi2  = (const float*)d_in[13];
    const float* bh2  = (const float*)d_in[14];
    const float* Whr2 = (const float*)d_in[15];
    const float* Wlin = (const float*)d_in[16];
    const float* blin = (const float*)d_in[17];

    char* wp = (char*)d_ws;
    size_t off = 0;
    auto alloc = [&](size_t bytes) -> char* {
        char* p = wp + off; off += (bytes + 255) & ~(size_t)255; return p;
    };
    short* B0   = (short*)alloc((size_t)G4H * 864 * 2);
    short* B1   = (short*)alloc((size_t)G4H * 1536 * 2);
    short* B2   = (short*)alloc((size_t)G4H * 1536 * 2);
    short* Wf   = (short*)alloc((size_t)256 * 768 * 2);
    float* bias = (float*)alloc((size_t)3 * G4H * 4);
    short* hid  = (short*)alloc((size_t)3 * 2 * Bn * Hn * 2);
    float* cst  = (float*)alloc((size_t)3 * Bn * Hn * 4);   // also absorbs hid overread

    hipLaunchKernelGGL(k_prep, dim3(1188), dim3(256), 0, stream,
                       Wih0, bi0, bh0, bi1, bh1, bi2, bh2, B0, bias);
    hipLaunchKernelGGL(k_init, dim3(1024), dim3(256), 0, stream, hid, cst);
    hipLaunchKernelGGL(k_fold, dim3(192 * 48), dim3(64), 0, stream, Whh0, Whr0, B0, 864, 0, 192);
    hipLaunchKernelGGL(k_fold, dim3(192 * 48), dim3(64), 0, stream, Wih1, Whr0, B1, 1536, 0, 192);
    hipLaunchKernelGGL(k_fold, dim3(192 * 48), dim3(64), 0, stream, Whh1, Whr1, B1, 1536, 768, 192);
    hipLaunchKernelGGL(k_fold, dim3(192 * 48), dim3(64), 0, stream, Wih2, Whr1, B2, 1536, 0, 192);
    hipLaunchKernelGGL(k_fold, dim3(192 * 48), dim3(64), 0, stream, Whh2, Whr2, B2, 1536, 768, 192);
    hipLaunchKernelGGL(k_fold, dim3(16 * 48), dim3(64), 0, stream, Wlin, Whr2, Wf, 768, 0, 16);

    for (int w = 0; w < 162; ++w)
        hipLaunchKernelGGL(k_step, dim3(NBLK), dim3(256), 0, stream,
                           x, B0, B1, B2, bias, hid, cst, w);

    const short* h2 = hid + (size_t)5 * Bn * Hn;
    hipLaunchKernelGGL(k_final, dim3(Bn), dim3(256), 0, stream, h2, Wf, blin, (float*)d_out);
}

// Round 9
// 5595.288 us; speedup vs baseline: 1.4698x; 1.2793x over previous
//
#include <hip/hip_runtime.h>
#include <stdint.h>

// Problem constants
#define Sn 64
#define Un 10
#define Tn 160
#define Fn 80
#define Bn 640      // S*U
#define Hn 768
#define Pn 256
#define En 256
#define G4H 3072
#define NBLK 480

using short8  = __attribute__((ext_vector_type(8))) short;
using short4v = __attribute__((ext_vector_type(4))) short;
using floatx4 = __attribute__((ext_vector_type(4))) float;

__device__ __forceinline__ short f2bf(float f){
    unsigned u = __builtin_bit_cast(unsigned, f);
    u += 0x7fffu + ((u >> 16) & 1u);
    return (short)(u >> 16);
}
__device__ __forceinline__ float bf2f(short s){
    return __builtin_bit_cast(float, ((unsigned)(unsigned short)s) << 16);
}
__device__ __forceinline__ float sigm(float x){ return 1.f / (1.f + __expf(-x)); }
__device__ __forceinline__ float tanh_(float x){
    float e = __expf(-2.f * fmaxf(x, -40.f));
    return (1.f - e) / (1.f + e);
}

// async global->LDS DMA, 16B per lane. LDS base wave-uniform (+lane*16 by HW);
// global source is PER-LANE.
__device__ __forceinline__ void gll(const short* g, short* l){
    __builtin_amdgcn_global_load_lds(
        (const __attribute__((address_space(1))) unsigned int*)(const void*)g,
        (__attribute__((address_space(3))) unsigned int*)(void*)l, 16, 0, 0);
}
#define VMW(N) asm volatile("s_waitcnt vmcnt(" #N ")" ::: "memory")
#define LGKM0  asm volatile("s_waitcnt lgkmcnt(0)" ::: "memory")

// Packed B layout (DMA consumption order), per layer with NSTG=KTOT/32:
//   element (ct, s, g, nt, lane, e) at (((ct*NSTG+s)*4+g)*3+nt)*512 + lane*8 + e
// where row = g*768 + ct*48 + nt*16 + (lane&15), k = s*32 + (lane>>4)*8 + e.
// Each gll then reads uniform_base + lane*16B -> dense sequential 1KB.

// ---------------- prep: bias sums + Wih0 -> B0 packed tail stages -----------
__global__ void k_prep(const float* __restrict__ Wih0,
                       const float* bi0, const float* bh0,
                       const float* bi1, const float* bh1,
                       const float* bi2, const float* bh2,
                       short* __restrict__ B0, float* __restrict__ bias){
    int i = blockIdx.x * 256 + threadIdx.x;
    const int W0 = G4H * 96;
    if (i < W0){
        int g = i / 96, c = i % 96;            // g: G4H row, k = 768+c
        int gg = g / 768, jj = g % 768;
        int ct = jj / 48, r = jj % 48, ntB = r / 16, lnB = r % 16;
        int k = 768 + c, s = k >> 5, lq = (k >> 3) & 3, e = k & 7;
        size_t off = ((((size_t)(ct * 27 + s)) * 4 + gg) * 3 + ntB) * 512
                   + (size_t)(lq * 16 + lnB) * 8 + e;
        B0[off] = (c < Fn) ? f2bf(Wih0[(size_t)g * Fn + c]) : (short)0;
    } else if (i < W0 + 3 * G4H){
        int j = i - W0; int l = j / G4H, g = j % G4H;
        const float* a = (l == 0) ? bi0 : (l == 1) ? bi1 : bi2;
        const float* b = (l == 0) ? bh0 : (l == 1) ? bh1 : bh2;
        bias[j] = a[g] + b[g];
    }
}

// ---------------- init: zero hidden (bf16) and c (fp32) ---------------------
__global__ void k_init(short* __restrict__ hidden, float* __restrict__ c){
    int i = blockIdx.x * 256 + threadIdx.x;
    int stride = gridDim.x * 256;
    const int NH = 3 * 2 * Bn * Hn;
    const int NC = 3 * Bn * Hn;
    for (int j = i; j < NH; j += stride) hidden[j] = 0;
    for (int j = i; j < NC; j += stride) c[j] = 0.f;
}

// ---------------- fold: out = A @ Whr^T (K=256); packed write if nstg>0 -----
__global__ void k_fold(const float* __restrict__ A, const float* __restrict__ Whr,
                       short* __restrict__ out, int ldout, int coloff, int Mtiles,
                       int nstg){
    int mt = blockIdx.x % Mtiles, nt = blockIdx.x / Mtiles;
    int lane = threadIdx.x & 63;
    int ln = lane & 15, lq = lane >> 4;
    floatx4 acc = {0.f, 0.f, 0.f, 0.f};
    const float* ap = A + (size_t)(mt * 16 + ln) * 256 + lq * 8;
    const float* bp = Whr + (size_t)(lq * 8) * 768 + nt * 16 + ln;
    for (int p0 = 0; p0 < 256; p0 += 32){
        short8 af, bf;
        #pragma unroll
        for (int j = 0; j < 8; ++j) af[j] = f2bf(ap[p0 + j]);
        #pragma unroll
        for (int j = 0; j < 8; ++j) bf[j] = f2bf(bp[(size_t)(p0 + j) * 768]);
        acc = __builtin_amdgcn_mfma_f32_16x16x32_bf16(af, bf, acc, 0, 0, 0);
    }
    #pragma unroll
    for (int r = 0; r < 4; ++r){
        int row = mt * 16 + lq * 4 + r, col = nt * 16 + ln;
        int k = coloff + col;
        if (nstg){
            int gg = row / 768, jj = row % 768;
            int ct = jj / 48, rr = jj % 48, ntB = rr / 16, lnB = rr % 16;
            int s = k >> 5, lqk = (k >> 3) & 3, e = k & 7;
            size_t off = ((((size_t)ct * nstg + s) * 4 + gg) * 3 + ntB) * 512
                       + (size_t)(lqk * 16 + lnB) * 8 + e;
            out[off] = f2bf(acc[r]);
        } else {
            out[(size_t)row * ldout + k] = f2bf(acc[r]);
        }
    }
}

// ---------------- per-wavefront step kernel: deep DMA pipeline, packed B ----
// 480 blocks x 256 thr (2 blocks/CU). layer=bid%3, r2=bid/3: mt=r2>>4 (64
// rows), ct=r2&15 (48 H-dims). Wave wg = gate wg.
// B: packed layout -> each gll is uniform_base + lane*16B (sequential 1KB);
//   4-slot ring (slot = stage&3), stage p+4 issued at phase p, consumed p+4.
//   Phase: VMW -> ds_read -> lgkmcnt(0) -> issue -> MFMA.
// A: 64 rows x 12 units (16B), rotate swizzle; double buffer, 1 chunk ahead.
// Steady ledger (per wave, in-order): entering chunk = 9 [B+1,B+2,B+3];
//   +A(3)=12; ph0 VMW(12), issue; ph1 VMW(12); ph2 VMW(12); end VMW(9).
__global__ __launch_bounds__(256, 4) void k_step(const float* __restrict__ x,
        const short* __restrict__ B0, const short* __restrict__ B1,
        const short* __restrict__ B2, const float* __restrict__ bias,
        short* __restrict__ hidden, float* __restrict__ c, int w){
    __shared__ __align__(16) short sB[4 * 6144];    // 49,152 B  B ring (4 slots)
    __shared__ __align__(16) short sAr[2 * 6144];   // 24,576 B  A dbuf 64x12 units
    float* sEx = (float*)sB;                        // overlay [4][32][49] fp32

    const int tid = threadIdx.x, lane = tid & 63, wg = tid >> 6;
    const int bid = blockIdx.x;
    const int layer = bid % 3;
    const int t = w - layer;
    if (t < 0 || t >= Tn) return;
    const int r2 = bid / 3;
    const int mt = r2 >> 4, ct = r2 & 15;
    const int m0 = mt * 64, j0 = ct * 48;
    const short* Bl = (layer == 0) ? B0 : (layer == 1) ? B1 : B2;
    const int NSTG = (layer == 0) ? 27 : 48;
    const int ln = lane & 15, lq = lane >> 4;
    const int rr = tid >> 2;
    const int pp = (w + 1) & 1;

    // per-lane packed-B base; stage/wg/nt add a uniform offset
    const short* bglane = Bl + (size_t)lane * 8;
    const int ctb = ct * NSTG;

    // A DMA lane mapping: unit u=(wg*3+j)*64+lane covers 64 rows x 12 units;
    // LDS unit (row,kc') <- global chunk kcg=(kc'-row)%12 (rotate swizzle).
    int aoffA[3];
    #pragma unroll
    for (int j = 0; j < 3; ++j){
        int u = (wg * 3 + j) * 64 + lane;
        int row = u / 12, kcp = u % 12;
        int kcg = kcp - (row % 12); if (kcg < 0) kcg += 12;
        aoffA[j] = row * Hn + kcg * 8;
    }
    // afr read: row = m4*16+ln; kc' = (row + ks*4+lq) % 12
    int prem[4];
    #pragma unroll
    for (int m4 = 0; m4 < 4; ++m4) prem[m4] = (m4 * 16 + ln) % 12;

    const short* srcA = (layer == 0) ? hidden + (size_t)pp * Bn * Hn
                       : hidden + (size_t)((layer - 1) * 2 + pp) * Bn * Hn;
    const short* srcH = hidden + (size_t)(layer * 2 + pp) * Bn * Hn;

    auto issueB = [&](int s){
        #pragma unroll
        for (int nt = 0; nt < 3; ++nt)
            gll(bglane + (size_t)((ctb + s) * 12 + wg * 3 + nt) * 512,
                &sB[(s & 3) * 6144 + (wg * 3 + nt) * 512]);
    };
    auto issueA = [&](int chn){
        const short* src; int jj;
        if (layer == 0 || chn < 8){ src = srcA; jj = chn * 96; }
        else { src = srcH; jj = chn * 96 - 768; }
        const short* gb = src + (size_t)m0 * Hn + jj;
        #pragma unroll
        for (int j = 0; j < 3; ++j)
            gll(gb + aoffA[j], &sAr[(chn & 1) * 6144 + (wg * 3 + j) * 512]);
    };

    floatx4 acc[4][3];
    #pragma unroll
    for (int nt = 0; nt < 3; ++nt){
        float bv = bias[layer * G4H + wg * Hn + j0 + nt * 16 + ln];
        #pragma unroll
        for (int m4 = 0; m4 < 4; ++m4){
            acc[m4][nt][0] = bv; acc[m4][nt][1] = bv;
            acc[m4][nt][2] = bv; acc[m4][nt][3] = bv;
        }
    }

// phase: VMW -> reads -> LGKM0 (pin read<DMA-issue) -> issue -> MFMA
#define PH(ks_, slot_, WAITN, ISSUE)                                            \
    {                                                                           \
        VMW(WAITN);                                                             \
        short8 bfr[3], afr[4];                                                  \
        _Pragma("unroll")                                                       \
        for (int nt = 0; nt < 3; ++nt)                                          \
            bfr[nt] = *(const short8*)&sB[(slot_) * 6144 + (wg * 3 + nt) * 512 + lane * 8]; \
        const int ksl_ = (ks_) * 4 + lq;                                        \
        _Pragma("unroll")                                                       \
        for (int m4 = 0; m4 < 4; ++m4){                                         \
            int idx = prem[m4] + ksl_; if (idx >= 12) idx -= 12;                \
            afr[m4] = *(const short8*)&sAr[abuf * 6144 + ((m4 * 16 + ln) * 12 + idx) * 8]; \
        }                                                                       \
        LGKM0;                                                                  \
        ISSUE;                                                                  \
        _Pragma("unroll")                                                       \
        for (int m4 = 0; m4 < 4; ++m4)                                          \
            _Pragma("unroll")                                                   \
            for (int nt = 0; nt < 3; ++nt)                                      \
                acc[m4][nt] = __builtin_amdgcn_mfma_f32_16x16x32_bf16(afr[m4], bfr[nt], acc[m4][nt], 0, 0, 0); \
    }

    // prologue: A(0) [3], B stages 0-3 [12]; VMW(12) retires A(0); barrier.
    issueA(0);
    issueB(0); issueB(1); issueB(2); issueB(3);
    VMW(12);
    __builtin_amdgcn_s_barrier();

    const int NST = (layer == 0) ? 7 : 14;   // steady chunks
    for (int ch = 0; ch < NST; ++ch){
        const int s0 = 3 * ch;
        const int abuf = ch & 1;
        issueA(ch + 1);
        PH(0, (s0 + 0) & 3, 12, issueB(s0 + 4));
        PH(1, (s0 + 1) & 3, 12, issueB(s0 + 5));
        PH(2, (s0 + 2) & 3, 12, issueB(s0 + 6));
        VMW(9);                      // retires B(s0+3) + A(ch+1)
        __builtin_amdgcn_s_barrier();
    }
    if (layer == 0){
        // chunk 7 (abuf=1): no A-issue (chunk 8 is x); B stages end at 26
        {
            const int abuf = 1;
            PH(0, 1, 9, issueB(25));
            PH(1, 2, 9, issueB(26));
            PH(2, 3, 9, (void)0);
            __builtin_amdgcn_s_barrier();
        }
        // x-insert into A buf 0 with rotate layout
        {
            const float* xr = x + ((size_t)(m0 + rr) * Tn + t) * Fn;
            int q3 = (tid & 3) * 3;
            #pragma unroll
            for (int ii = 0; ii < 3; ++ii){
                int kcg = q3 + ii;          // global chunk 0..11
                int f = kcg * 8;
                short8 v = {0,0,0,0,0,0,0,0};
                if (f < Fn){
                    float4 a = *(const float4*)(xr + f);
                    float4 b = *(const float4*)(xr + f + 4);
                    v[0]=f2bf(a.x); v[1]=f2bf(a.y); v[2]=f2bf(a.z); v[3]=f2bf(a.w);
                    v[4]=f2bf(b.x); v[5]=f2bf(b.y); v[6]=f2bf(b.z); v[7]=f2bf(b.w);
                }
                int kcp = kcg + (rr % 12); if (kcp >= 12) kcp -= 12;
                *(short8*)&sAr[(rr * 12 + kcp) * 8] = v;
            }
            LGKM0;
            __builtin_amdgcn_s_barrier();
        }
        // chunk 8 (abuf=0): tail, entering [B24,B25,B26]=9
        {
            const int abuf = 0;
            PH(0, 0, 6, (void)0);
            PH(1, 1, 3, (void)0);
            PH(2, 2, 0, (void)0);
            __builtin_amdgcn_s_barrier();
        }
    } else {
        // chunk 14 (abuf=0): A(15) + partial B issue (stages end at 47)
        {
            const int abuf = 0;
            issueA(15);
            PH(0, 2, 12, issueB(46));
            PH(1, 3, 12, issueB(47));
            PH(2, 0, 12, (void)0);
            VMW(6);                  // retires B45 + A(15)
            __builtin_amdgcn_s_barrier();
        }
        // chunk 15 (abuf=1): tail, entering [B46,B47]=6
        {
            const int abuf = 1;
            PH(0, 1, 6, (void)0);
            PH(1, 2, 3, (void)0);
            PH(2, 3, 0, (void)0);
            __builtin_amdgcn_s_barrier();
        }
    }
#undef PH

    // ---- epilogue: 2-phase gate exchange (sEx overlays sB; all DMA drained) ----
    #pragma unroll
    for (int p = 0; p < 2; ++p){
        if (p) __syncthreads();
        #pragma unroll
        for (int mm = 0; mm < 2; ++mm){
            int m4 = p * 2 + mm;
            #pragma unroll
            for (int nt = 0; nt < 3; ++nt)
                #pragma unroll
                for (int r = 0; r < 4; ++r)
                    sEx[(wg * 32 + mm * 16 + lq * 4 + r) * 49 + nt * 16 + ln] = acc[m4][nt][r];
        }
        __syncthreads();
        {
            int r32 = tid >> 3, cbp = (tid & 7) * 6;
            int row = p * 32 + r32;
            float* cp = c + ((size_t)layer * Bn + (m0 + row)) * Hn + j0 + cbp;
            short hb[6];
            #pragma unroll
            for (int ii = 0; ii < 6; ++ii){
                int cc_ = cbp + ii;
                float gi = sEx[(0 * 32 + r32) * 49 + cc_];
                float gf = sEx[(1 * 32 + r32) * 49 + cc_];
                float gg = sEx[(2 * 32 + r32) * 49 + cc_];
                float go = sEx[(3 * 32 + r32) * 49 + cc_];
                float cv = sigm(gf) * cp[ii] + sigm(gi) * tanh_(gg);
                cp[ii] = cv;
                hb[ii] = f2bf(sigm(go) * tanh_(cv));
            }
            short* hp = hidden + ((size_t)(layer * 2 + (w & 1)) * Bn + (m0 + row)) * Hn + j0 + cbp;
            #pragma unroll
            for (int q = 0; q < 3; ++q){
                unsigned v = (unsigned)(unsigned short)hb[q * 2] |
                             ((unsigned)(unsigned short)hb[q * 2 + 1] << 16);
                *(unsigned*)&hp[q * 2] = v;
            }
        }
    }
}

// ---------------- final: emb = normalize(relu(hidden2_last @ Wf^T + b)) -----
__global__ void k_final(const short* __restrict__ h2, const short* __restrict__ Wf,
                        const float* __restrict__ blin, float* __restrict__ out){
    __shared__ __align__(16) short sH[768];
    __shared__ float sW[4];
    int b = blockIdx.x, e = threadIdx.x;
    if (e < 96) *(short8*)&sH[e * 8] = *(const short8*)&h2[(size_t)b * 768 + e * 8];
    __syncthreads();
    float acc = blin[e];
    const short* wr = Wf + (size_t)e * 768;
    for (int j = 0; j < 768; j += 8){
        short8 hv = *(const short8*)&sH[j];
        short8 wv = *(const short8*)&wr[j];
        #pragma unroll
        for (int k = 0; k < 8; ++k) acc += bf2f(hv[k]) * bf2f(wv[k]);
    }
    float v = fmaxf(acc, 0.f);
    float s = v * v;
    #pragma unroll
    for (int off = 32; off >= 1; off >>= 1) s += __shfl_down(s, off);
    if ((e & 63) == 0) sW[e >> 6] = s;
    __syncthreads();
    float tot = sW[0] + sW[1] + sW[2] + sW[3];
    float scale = 1.f / fmaxf(sqrtf(tot), 1e-12f);
    out[(size_t)b * 256 + e] = v * scale;
}

// ---------------- host launcher ---------------------------------------------
extern "C" void kernel_launch(void* const* d_in, const int* in_sizes, int n_in,
                              void* d_out, int out_size, void* d_ws, size_t ws_size,
                              hipStream_t stream){
    const float* x    = (const float*)d_in[0];
    const float* Wih0 = (const float*)d_in[1];
    const float* Whh0 = (const float*)d_in[2];
    const float* bi0  = (const float*)d_in[3];
    const float* bh0  = (const float*)d_in[4];
    const float* Whr0 = (const float*)d_in[5];
    const float* Wih1 = (const float*)d_in[6];
    const float* Whh1 = (const float*)d_in[7];
    const float* bi1  = (const float*)d_in[8];
    const float* bh1  = (const float*)d_in[9];
    const float* Whr1 = (const float*)d_in[10];
    const float* Wih2 = (const float*)d_in[11];
    const float* Whh2 = (const float*)d_in[12];
    const float* bi2  = (const float*)d_in[13];
    const float* bh2  = (const float*)d_in[14];
    const float* Whr2 = (const float*)d_in[15];
    const float* Wlin = (const float*)d_in[16];
    const float* blin = (const float*)d_in[17];

    char* wp = (char*)d_ws;
    size_t off = 0;
    auto alloc = [&](size_t bytes) -> char* {
        char* p = wp + off; off += (bytes + 255) & ~(size_t)255; return p;
    };
    short* B0   = (short*)alloc((size_t)G4H * 864 * 2);
    short* B1   = (short*)alloc((size_t)G4H * 1536 * 2);
    short* B2   = (short*)alloc((size_t)G4H * 1536 * 2);
    short* Wf   = (short*)alloc((size_t)256 * 768 * 2);
    float* bias = (float*)alloc((size_t)3 * G4H * 4);
    short* hid  = (short*)alloc((size_t)3 * 2 * Bn * Hn * 2);
    float* cst  = (float*)alloc((size_t)3 * Bn * Hn * 4);   // also absorbs hid overread

    hipLaunchKernelGGL(k_prep, dim3(1188), dim3(256), 0, stream,
                       Wih0, bi0, bh0, bi1, bh1, bi2, bh2, B0, bias);
    hipLaunchKernelGGL(k_init, dim3(1024), dim3(256), 0, stream, hid, cst);
    // folds (packed): R_l = Whh_l @ Whr_l ; U_l = Wih_l @ Whr_{l-1}
    hipLaunchKernelGGL(k_fold, dim3(192 * 48), dim3(64), 0, stream, Whh0, Whr0, B0, 0, 0,   192, 27);
    hipLaunchKernelGGL(k_fold, dim3(192 * 48), dim3(64), 0, stream, Wih1, Whr0, B1, 0, 0,   192, 48);
    hipLaunchKernelGGL(k_fold, dim3(192 * 48), dim3(64), 0, stream, Whh1, Whr1, B1, 0, 768, 192, 48);
    hipLaunchKernelGGL(k_fold, dim3(192 * 48), dim3(64), 0, stream, Wih2, Whr1, B2, 0, 0,   192, 48);
    hipLaunchKernelGGL(k_fold, dim3(192 * 48), dim3(64), 0, stream, Whh2, Whr2, B2, 0, 768, 192, 48);
    // Wf stays linear (k_final reads row-major)
    hipLaunchKernelGGL(k_fold, dim3(16 * 48), dim3(64), 0, stream, Wlin, Whr2, Wf, 768, 0, 16, 0);

    for (int w = 0; w < 162; ++w)
        hipLaunchKernelGGL(k_step, dim3(NBLK), dim3(256), 0, stream,
                           x, B0, B1, B2, bias, hid, cst, w);

    const short* h2 = hid + (size_t)5 * Bn * Hn;
    hipLaunchKernelGGL(k_final, dim3(Bn), dim3(256), 0, stream, h2, Wf, blin, (float*)d_out);
}

// Round 10
// 5479.768 us; speedup vs baseline: 1.5008x; 1.0211x over previous
//
#include <hip/hip_runtime.h>
#include <stdint.h>

// Problem constants
#define Sn 64
#define Un 10
#define Tn 160
#define Fn 80
#define Bn 640      // S*U
#define Hn 768
#define Pn 256
#define En 256
#define G4H 3072
#define NBLK 480

using short8  = __attribute__((ext_vector_type(8))) short;
using short4v = __attribute__((ext_vector_type(4))) short;
using floatx4 = __attribute__((ext_vector_type(4))) float;

__device__ __forceinline__ short f2bf(float f){
    unsigned u = __builtin_bit_cast(unsigned, f);
    u += 0x7fffu + ((u >> 16) & 1u);
    return (short)(u >> 16);
}
__device__ __forceinline__ float bf2f(short s){
    return __builtin_bit_cast(float, ((unsigned)(unsigned short)s) << 16);
}
__device__ __forceinline__ float sigm(float x){ return 1.f / (1.f + __expf(-x)); }
__device__ __forceinline__ float tanh_(float x){
    float e = __expf(-2.f * fmaxf(x, -40.f));
    return (1.f - e) / (1.f + e);
}

// async global->LDS DMA, 16B per lane. LDS base wave-uniform (+lane*16 by HW);
// global source is PER-LANE.
__device__ __forceinline__ void gll(const short* g, short* l){
    __builtin_amdgcn_global_load_lds(
        (const __attribute__((address_space(1))) unsigned int*)(const void*)g,
        (__attribute__((address_space(3))) unsigned int*)(void*)l, 16, 0, 0);
}
#define VMW(N) asm volatile("s_waitcnt vmcnt(" #N ")" ::: "memory")
#define LGKM0  asm volatile("s_waitcnt lgkmcnt(0)" ::: "memory")

// Packed B layout (DMA consumption order), per layer with NSTG=KTOT/32:
//   element (ct, s, g, nt, lane, e) at (((ct*NSTG+s)*4+g)*3+nt)*512 + lane*8 + e
// where row = g*768 + ct*48 + nt*16 + (lane&15), k = s*32 + (lane>>4)*8 + e.
// Packed hidden layout (chunk-major, A DMA consumption order):
//   hid[layer][parity][mt(10)][ch(8)][row(64)][col(96)]  (all chunks 12KB dense)

// ---------------- prep: bias sums + Wih0 -> B0 packed tail stages -----------
__global__ void k_prep(const float* __restrict__ Wih0,
                       const float* bi0, const float* bh0,
                       const float* bi1, const float* bh1,
                       const float* bi2, const float* bh2,
                       short* __restrict__ B0, float* __restrict__ bias){
    int i = blockIdx.x * 256 + threadIdx.x;
    const int W0 = G4H * 96;
    if (i < W0){
        int g = i / 96, c = i % 96;            // g: G4H row, k = 768+c
        int gg = g / 768, jj = g % 768;
        int ct = jj / 48, r = jj % 48, ntB = r / 16, lnB = r % 16;
        int k = 768 + c, s = k >> 5, lq = (k >> 3) & 3, e = k & 7;
        size_t off = ((((size_t)(ct * 27 + s)) * 4 + gg) * 3 + ntB) * 512
                   + (size_t)(lq * 16 + lnB) * 8 + e;
        B0[off] = (c < Fn) ? f2bf(Wih0[(size_t)g * Fn + c]) : (short)0;
    } else if (i < W0 + 3 * G4H){
        int j = i - W0; int l = j / G4H, g = j % G4H;
        const float* a = (l == 0) ? bi0 : (l == 1) ? bi1 : bi2;
        const float* b = (l == 0) ? bh0 : (l == 1) ? bh1 : bh2;
        bias[j] = a[g] + b[g];
    }
}

// ---------------- init: zero hidden (bf16) and c (fp32) ---------------------
__global__ void k_init(short* __restrict__ hidden, float* __restrict__ c){
    int i = blockIdx.x * 256 + threadIdx.x;
    int stride = gridDim.x * 256;
    const int NH = 3 * 2 * Bn * Hn;
    const int NC = 3 * Bn * Hn;
    for (int j = i; j < NH; j += stride) hidden[j] = 0;
    for (int j = i; j < NC; j += stride) c[j] = 0.f;
}

// ---------------- fold: out = A @ Whr^T (K=256); packed write if nstg>0 -----
__global__ void k_fold(const float* __restrict__ A, const float* __restrict__ Whr,
                       short* __restrict__ out, int ldout, int coloff, int Mtiles,
                       int nstg){
    int mt = blockIdx.x % Mtiles, nt = blockIdx.x / Mtiles;
    int lane = threadIdx.x & 63;
    int ln = lane & 15, lq = lane >> 4;
    floatx4 acc = {0.f, 0.f, 0.f, 0.f};
    const float* ap = A + (size_t)(mt * 16 + ln) * 256 + lq * 8;
    const float* bp = Whr + (size_t)(lq * 8) * 768 + nt * 16 + ln;
    for (int p0 = 0; p0 < 256; p0 += 32){
        short8 af, bf;
        #pragma unroll
        for (int j = 0; j < 8; ++j) af[j] = f2bf(ap[p0 + j]);
        #pragma unroll
        for (int j = 0; j < 8; ++j) bf[j] = f2bf(bp[(size_t)(p0 + j) * 768]);
        acc = __builtin_amdgcn_mfma_f32_16x16x32_bf16(af, bf, acc, 0, 0, 0);
    }
    #pragma unroll
    for (int r = 0; r < 4; ++r){
        int row = mt * 16 + lq * 4 + r, col = nt * 16 + ln;
        int k = coloff + col;
        if (nstg){
            int gg = row / 768, jj = row % 768;
            int ct = jj / 48, rr = jj % 48, ntB = rr / 16, lnB = rr % 16;
            int s = k >> 5, lqk = (k >> 3) & 3, e = k & 7;
            size_t off = ((((size_t)ct * nstg + s) * 4 + gg) * 3 + ntB) * 512
                       + (size_t)(lqk * 16 + lnB) * 8 + e;
            out[off] = f2bf(acc[r]);
        } else {
            out[(size_t)row * ldout + k] = f2bf(acc[r]);
        }
    }
}

// ---------------- per-wavefront step kernel: deep DMA pipeline, all packed --
// 480 blocks x 256 thr (2 blocks/CU). layer=bid%3, r2=bid/3: mt=r2>>4 (64
// rows), ct=r2&15 (48 H-dims). Wave wg = gate wg.
// B: packed -> each gll uniform_base + lane*16B (sequential 1KB); 4-slot ring.
// A: hidden chunk-major -> each 12KB chunk contiguous; gll lanes cover a
//   contiguous ~1KB window (rotate swizzle permutes only within rows).
//   LDS layout unchanged: unit u holds (row=u/12, kc'=u%12), kcg=(kc'-row)%12.
// Steady ledger (per wave, in-order): entering chunk = 9 [B+1,B+2,B+3];
//   +A(3)=12; ph0 VMW(12), issue; ph1 VMW(12); ph2 VMW(12); end VMW(9).
__global__ __launch_bounds__(256, 4) void k_step(const float* __restrict__ x,
        const short* __restrict__ B0, const short* __restrict__ B1,
        const short* __restrict__ B2, const float* __restrict__ bias,
        short* __restrict__ hidden, float* __restrict__ c, int w){
    __shared__ __align__(16) short sB[4 * 6144];    // 49,152 B  B ring (4 slots)
    __shared__ __align__(16) short sAr[2 * 6144];   // 24,576 B  A dbuf 64x12 units
    float* sEx = (float*)sB;                        // overlay [4][32][49] fp32

    const int tid = threadIdx.x, lane = tid & 63, wg = tid >> 6;
    const int bid = blockIdx.x;
    const int layer = bid % 3;
    const int t = w - layer;
    if (t < 0 || t >= Tn) return;
    const int r2 = bid / 3;
    const int mt = r2 >> 4, ct = r2 & 15;
    const int m0 = mt * 64, j0 = ct * 48;
    const short* Bl = (layer == 0) ? B0 : (layer == 1) ? B1 : B2;
    const int NSTG = (layer == 0) ? 27 : 48;
    const int ln = lane & 15, lq = lane >> 4;
    const int rr = tid >> 2;
    const int pp = (w + 1) & 1;

    // per-lane packed-B base; stage/wg/nt add a uniform offset
    const short* bglane = Bl + (size_t)lane * 8;
    const int ctb = ct * NSTG;

    // A DMA lane mapping (within a contiguous 12KB chunk block):
    // unit u=(wg*3+j)*64+lane -> row=u/12, kc'=u%12; source unit kcg=(kc'-row)%12
    int aoffA[3];
    #pragma unroll
    for (int j = 0; j < 3; ++j){
        int u = (wg * 3 + j) * 64 + lane;
        int row = u / 12, kcp = u % 12;
        int kcg = kcp - (row % 12); if (kcg < 0) kcg += 12;
        aoffA[j] = row * 96 + kcg * 8;
    }
    // afr read: row = m4*16+ln; kc' = (row + ks*4+lq) % 12
    int prem[4];
    #pragma unroll
    for (int m4 = 0; m4 < 4; ++m4) prem[m4] = (m4 * 16 + ln) % 12;

    const short* srcA = (layer == 0) ? hidden + (size_t)pp * Bn * Hn
                       : hidden + (size_t)((layer - 1) * 2 + pp) * Bn * Hn;
    const short* srcH = hidden + (size_t)(layer * 2 + pp) * Bn * Hn;

    auto issueB = [&](int s){
        #pragma unroll
        for (int nt = 0; nt < 3; ++nt)
            gll(bglane + (size_t)((ctb + s) * 12 + wg * 3 + nt) * 512,
                &sB[(s & 3) * 6144 + (wg * 3 + nt) * 512]);
    };
    auto issueA = [&](int chn){
        const short* src; int chg;
        if (layer == 0 || chn < 8){ src = srcA; chg = chn; }
        else { src = srcH; chg = chn - 8; }
        const short* gb = src + (size_t)(mt * 8 + chg) * 6144;
        #pragma unroll
        for (int j = 0; j < 3; ++j)
            gll(gb + aoffA[j], &sAr[(chn & 1) * 6144 + (wg * 3 + j) * 512]);
    };

    floatx4 acc[4][3];
    #pragma unroll
    for (int nt = 0; nt < 3; ++nt){
        float bv = bias[layer * G4H + wg * Hn + j0 + nt * 16 + ln];
        #pragma unroll
        for (int m4 = 0; m4 < 4; ++m4){
            acc[m4][nt][0] = bv; acc[m4][nt][1] = bv;
            acc[m4][nt][2] = bv; acc[m4][nt][3] = bv;
        }
    }

// phase: VMW -> reads -> LGKM0 (pin read<DMA-issue) -> issue -> MFMA
#define PH(ks_, slot_, WAITN, ISSUE)                                            \
    {                                                                           \
        VMW(WAITN);                                                             \
        short8 bfr[3], afr[4];                                                  \
        _Pragma("unroll")                                                       \
        for (int nt = 0; nt < 3; ++nt)                                          \
            bfr[nt] = *(const short8*)&sB[(slot_) * 6144 + (wg * 3 + nt) * 512 + lane * 8]; \
        const int ksl_ = (ks_) * 4 + lq;                                        \
        _Pragma("unroll")                                                       \
        for (int m4 = 0; m4 < 4; ++m4){                                         \
            int idx = prem[m4] + ksl_; if (idx >= 12) idx -= 12;                \
            afr[m4] = *(const short8*)&sAr[abuf * 6144 + ((m4 * 16 + ln) * 12 + idx) * 8]; \
        }                                                                       \
        LGKM0;                                                                  \
        ISSUE;                                                                  \
        _Pragma("unroll")                                                       \
        for (int m4 = 0; m4 < 4; ++m4)                                          \
            _Pragma("unroll")                                                   \
            for (int nt = 0; nt < 3; ++nt)                                      \
                acc[m4][nt] = __builtin_amdgcn_mfma_f32_16x16x32_bf16(afr[m4], bfr[nt], acc[m4][nt], 0, 0, 0); \
    }

    // prologue: A(0) [3], B stages 0-3 [12]; VMW(12) retires A(0); barrier.
    issueA(0);
    issueB(0); issueB(1); issueB(2); issueB(3);
    VMW(12);
    __builtin_amdgcn_s_barrier();

    const int NST = (layer == 0) ? 7 : 14;   // steady chunks
    for (int ch = 0; ch < NST; ++ch){
        const int s0 = 3 * ch;
        const int abuf = ch & 1;
        issueA(ch + 1);
        PH(0, (s0 + 0) & 3, 12, issueB(s0 + 4));
        PH(1, (s0 + 1) & 3, 12, issueB(s0 + 5));
        PH(2, (s0 + 2) & 3, 12, issueB(s0 + 6));
        VMW(9);                      // retires B(s0+3) + A(ch+1)
        __builtin_amdgcn_s_barrier();
    }
    if (layer == 0){
        // chunk 7 (abuf=1): no A-issue (chunk 8 is x); B stages end at 26
        {
            const int abuf = 1;
            PH(0, 1, 9, issueB(25));
            PH(1, 2, 9, issueB(26));
            PH(2, 3, 9, (void)0);
            __builtin_amdgcn_s_barrier();
        }
        // x-insert into A buf 0 with rotate layout
        {
            const float* xr = x + ((size_t)(m0 + rr) * Tn + t) * Fn;
            int q3 = (tid & 3) * 3;
            #pragma unroll
            for (int ii = 0; ii < 3; ++ii){
                int kcg = q3 + ii;          // global chunk 0..11
                int f = kcg * 8;
                short8 v = {0,0,0,0,0,0,0,0};
                if (f < Fn){
                    float4 a = *(const float4*)(xr + f);
                    float4 b = *(const float4*)(xr + f + 4);
                    v[0]=f2bf(a.x); v[1]=f2bf(a.y); v[2]=f2bf(a.z); v[3]=f2bf(a.w);
                    v[4]=f2bf(b.x); v[5]=f2bf(b.y); v[6]=f2bf(b.z); v[7]=f2bf(b.w);
                }
                int kcp = kcg + (rr % 12); if (kcp >= 12) kcp -= 12;
                *(short8*)&sAr[(rr * 12 + kcp) * 8] = v;
            }
            LGKM0;
            __builtin_amdgcn_s_barrier();
        }
        // chunk 8 (abuf=0): tail, entering [B24,B25,B26]=9
        {
            const int abuf = 0;
            PH(0, 0, 6, (void)0);
            PH(1, 1, 3, (void)0);
            PH(2, 2, 0, (void)0);
            __builtin_amdgcn_s_barrier();
        }
    } else {
        // chunk 14 (abuf=0): A(15) + partial B issue (stages end at 47)
        {
            const int abuf = 0;
            issueA(15);
            PH(0, 2, 12, issueB(46));
            PH(1, 3, 12, issueB(47));
            PH(2, 0, 12, (void)0);
            VMW(6);                  // retires B45 + A(15)
            __builtin_amdgcn_s_barrier();
        }
        // chunk 15 (abuf=1): tail, entering [B46,B47]=6
        {
            const int abuf = 1;
            PH(0, 1, 6, (void)0);
            PH(1, 2, 3, (void)0);
            PH(2, 3, 0, (void)0);
            __builtin_amdgcn_s_barrier();
        }
    }
#undef PH

    // ---- epilogue: 2-phase gate exchange (sEx overlays sB; all DMA drained) ----
    #pragma unroll
    for (int p = 0; p < 2; ++p){
        if (p) __syncthreads();
        #pragma unroll
        for (int mm = 0; mm < 2; ++mm){
            int m4 = p * 2 + mm;
            #pragma unroll
            for (int nt = 0; nt < 3; ++nt)
                #pragma unroll
                for (int r = 0; r < 4; ++r)
                    sEx[(wg * 32 + mm * 16 + lq * 4 + r) * 49 + nt * 16 + ln] = acc[m4][nt][r];
        }
        __syncthreads();
        {
            int r32 = tid >> 3, cbp = (tid & 7) * 6;
            int row = p * 32 + r32;
            float* cp = c + ((size_t)layer * Bn + (m0 + row)) * Hn + j0 + cbp;
            short hb[6];
            #pragma unroll
            for (int ii = 0; ii < 6; ++ii){
                int cc_ = cbp + ii;
                float gi = sEx[(0 * 32 + r32) * 49 + cc_];
                float gf = sEx[(1 * 32 + r32) * 49 + cc_];
                float gg = sEx[(2 * 32 + r32) * 49 + cc_];
                float go = sEx[(3 * 32 + r32) * 49 + cc_];
                float cv = sigm(gf) * cp[ii] + sigm(gi) * tanh_(gg);
                cp[ii] = cv;
                hb[ii] = f2bf(sigm(go) * tanh_(cv));
            }
            // chunk-major h write: chunk ct>>1, col (ct&1)*48 + cbp
            short* hbase = hidden + (size_t)(layer * 2 + (w & 1)) * Bn * Hn;
            short* hp = hbase + ((size_t)((mt * 8 + (ct >> 1)) * 64 + row) * 96
                                 + (ct & 1) * 48 + cbp);
            #pragma unroll
            for (int q = 0; q < 3; ++q){
                unsigned v = (unsigned)(unsigned short)hb[q * 2] |
                             ((unsigned)(unsigned short)hb[q * 2 + 1] << 16);
                *(unsigned*)&hp[q * 2] = v;
            }
        }
    }
}

// ---------------- final: emb = normalize(relu(hidden2_last @ Wf^T + b)) -----
__global__ void k_final(const short* __restrict__ h2, const short* __restrict__ Wf,
                        const float* __restrict__ blin, float* __restrict__ out){
    __shared__ __align__(16) short sH[768];
    __shared__ float sW[4];
    int b = blockIdx.x, e = threadIdx.x;
    if (e < 96){
        int mtb = b >> 6, rowb = b & 63;
        *(short8*)&sH[e * 8] = *(const short8*)
            &h2[((size_t)(mtb * 8 + e / 12) * 64 + rowb) * 96 + (e % 12) * 8];
    }
    __syncthreads();
    float acc = blin[e];
    const short* wr = Wf + (size_t)e * 768;
    for (int j = 0; j < 768; j += 8){
        short8 hv = *(const short8*)&sH[j];
        short8 wv = *(const short8*)&wr[j];
        #pragma unroll
        for (int k = 0; k < 8; ++k) acc += bf2f(hv[k]) * bf2f(wv[k]);
    }
    float v = fmaxf(acc, 0.f);
    float s = v * v;
    #pragma unroll
    for (int off = 32; off >= 1; off >>= 1) s += __shfl_down(s, off);
    if ((e & 63) == 0) sW[e >> 6] = s;
    __syncthreads();
    float tot = sW[0] + sW[1] + sW[2] + sW[3];
    float scale = 1.f / fmaxf(sqrtf(tot), 1e-12f);
    out[(size_t)b * 256 + e] = v * scale;
}

// ---------------- host launcher ---------------------------------------------
extern "C" void kernel_launch(void* const* d_in, const int* in_sizes, int n_in,
                              void* d_out, int out_size, void* d_ws, size_t ws_size,
                              hipStream_t stream){
    const float* x    = (const float*)d_in[0];
    const float* Wih0 = (const float*)d_in[1];
    const float* Whh0 = (const float*)d_in[2];
    const float* bi0  = (const float*)d_in[3];
    const float* bh0  = (const float*)d_in[4];
    const float* Whr0 = (const float*)d_in[5];
    const float* Wih1 = (const float*)d_in[6];
    const float* Whh1 = (const float*)d_in[7];
    const float* bi1  = (const float*)d_in[8];
    const float* bh1  = (const float*)d_in[9];
    const float* Whr1 = (const float*)d_in[10];
    const float* Wih2 = (const float*)d_in[11];
    const float* Whh2 = (const float*)d_in[12];
    const float* bi2  = (const float*)d_in[13];
    const float* bh2  = (const float*)d_in[14];
    const float* Whr2 = (const float*)d_in[15];
    const float* Wlin = (const float*)d_in[16];
    const float* blin = (const float*)d_in[17];

    char* wp = (char*)d_ws;
    size_t off = 0;
    auto alloc = [&](size_t bytes) -> char* {
        char* p = wp + off; off += (bytes + 255) & ~(size_t)255; return p;
    };
    short* B0   = (short*)alloc((size_t)G4H * 864 * 2);
    short* B1   = (short*)alloc((size_t)G4H * 1536 * 2);
    short* B2   = (short*)alloc((size_t)G4H * 1536 * 2);
    short* Wf   = (short*)alloc((size_t)256 * 768 * 2);
    float* bias = (float*)alloc((size_t)3 * G4H * 4);
    short* hid  = (short*)alloc((size_t)3 * 2 * Bn * Hn * 2);
    float* cst  = (float*)alloc((size_t)3 * Bn * Hn * 4);

    hipLaunchKernelGGL(k_prep, dim3(1188), dim3(256), 0, stream,
                       Wih0, bi0, bh0, bi1, bh1, bi2, bh2, B0, bias);
    hipLaunchKernelGGL(k_init, dim3(1024), dim3(256), 0, stream, hid, cst);
    // folds (packed): R_l = Whh_l @ Whr_l ; U_l = Wih_l @ Whr_{l-1}
    hipLaunchKernelGGL(k_fold, dim3(192 * 48), dim3(64), 0, stream, Whh0, Whr0, B0, 0, 0,   192, 27);
    hipLaunchKernelGGL(k_fold, dim3(192 * 48), dim3(64), 0, stream, Wih1, Whr0, B1, 0, 0,   192, 48);
    hipLaunchKernelGGL(k_fold, dim3(192 * 48), dim3(64), 0, stream, Whh1, Whr1, B1, 0, 768, 192, 48);
    hipLaunchKernelGGL(k_fold, dim3(192 * 48), dim3(64), 0, stream, Wih2, Whr1, B2, 0, 0,   192, 48);
    hipLaunchKernelGGL(k_fold, dim3(192 * 48), dim3(64), 0, stream, Whh2, Whr2, B2, 0, 768, 192, 48);
    // Wf stays linear (k_final reads row-major)
    hipLaunchKernelGGL(k_fold, dim3(16 * 48), dim3(64), 0, stream, Wlin, Whr2, Wf, 768, 0, 16, 0);

    for (int w = 0; w < 162; ++w)
        hipLaunchKernelGGL(k_step, dim3(NBLK), dim3(256), 0, stream,
                           x, B0, B1, B2, bias, hid, cst, w);

    const short* h2 = hid + (size_t)5 * Bn * Hn;   // layer 2, parity 1, chunk-major
    hipLaunchKernelGGL(k_final, dim3(Bn), dim3(256), 0, stream, h2, Wf, blin, (float*)d_out);
}

// Round 11
// 4066.387 us; speedup vs baseline: 2.0225x; 1.3476x over previous
//
#include <hip/hip_runtime.h>
#include <stdint.h>

// Problem constants
#define Sn 64
#define Un 10
#define Tn 160
#define Fn 80
#define Bn 640      // S*U
#define Hn 768
#define Pn 256
#define En 256
#define G4H 3072
#define NBLK 480

using short8  = __attribute__((ext_vector_type(8))) short;
using short4v = __attribute__((ext_vector_type(4))) short;
using floatx4 = __attribute__((ext_vector_type(4))) float;

__device__ __forceinline__ short f2bf(float f){
    unsigned u = __builtin_bit_cast(unsigned, f);
    u += 0x7fffu + ((u >> 16) & 1u);
    return (short)(u >> 16);
}
__device__ __forceinline__ float bf2f(short s){
    return __builtin_bit_cast(float, ((unsigned)(unsigned short)s) << 16);
}
__device__ __forceinline__ float sigm(float x){ return 1.f / (1.f + __expf(-x)); }
__device__ __forceinline__ float tanh_(float x){
    float e = __expf(-2.f * fmaxf(x, -40.f));
    return (1.f - e) / (1.f + e);
}

// async global->LDS DMA, 16B per lane (A tiles only now).
__device__ __forceinline__ void gll(const short* g, short* l){
    __builtin_amdgcn_global_load_lds(
        (const __attribute__((address_space(1))) unsigned int*)(const void*)g,
        (__attribute__((address_space(3))) unsigned int*)(void*)l, 16, 0, 0);
}
#define VMW(N) asm volatile("s_waitcnt vmcnt(" #N ")" ::: "memory")
#define LGKM0  asm volatile("s_waitcnt lgkmcnt(0)" ::: "memory")

// Packed B layout (DMA/register consumption order), per layer, NSTG=KTOT/32:
//   element (ct, s, g, nt, lane, e) at (((ct*NSTG+s)*4+g)*3+nt)*512 + lane*8 + e
// Packed hidden layout (chunk-major): hid[layer][parity][mt(10)][ch(8)][64][96]

// ---------------- prep: bias sums + Wih0 -> B0 packed tail stages -----------
__global__ void k_prep(const float* __restrict__ Wih0,
                       const float* bi0, const float* bh0,
                       const float* bi1, const float* bh1,
                       const float* bi2, const float* bh2,
                       short* __restrict__ B0, float* __restrict__ bias){
    int i = blockIdx.x * 256 + threadIdx.x;
    const int W0 = G4H * 96;
    if (i < W0){
        int g = i / 96, c = i % 96;            // g: G4H row, k = 768+c
        int gg = g / 768, jj = g % 768;
        int ct = jj / 48, r = jj % 48, ntB = r / 16, lnB = r % 16;
        int k = 768 + c, s = k >> 5, lq = (k >> 3) & 3, e = k & 7;
        size_t off = ((((size_t)(ct * 27 + s)) * 4 + gg) * 3 + ntB) * 512
                   + (size_t)(lq * 16 + lnB) * 8 + e;
        B0[off] = (c < Fn) ? f2bf(Wih0[(size_t)g * Fn + c]) : (short)0;
    } else if (i < W0 + 3 * G4H){
        int j = i - W0; int l = j / G4H, g = j % G4H;
        const float* a = (l == 0) ? bi0 : (l == 1) ? bi1 : bi2;
        const float* b = (l == 0) ? bh0 : (l == 1) ? bh1 : bh2;
        bias[j] = a[g] + b[g];
    }
}

// ---------------- init: zero hidden (bf16) and c (fp32) ---------------------
__global__ void k_init(short* __restrict__ hidden, float* __restrict__ c){
    int i = blockIdx.x * 256 + threadIdx.x;
    int stride = gridDim.x * 256;
    const int NH = 3 * 2 * Bn * Hn;
    const int NC = 3 * Bn * Hn;
    for (int j = i; j < NH; j += stride) hidden[j] = 0;
    for (int j = i; j < NC; j += stride) c[j] = 0.f;
}

// ---------------- fold: out = A @ Whr^T (K=256); packed write if nstg>0 -----
__global__ void k_fold(const float* __restrict__ A, const float* __restrict__ Whr,
                       short* __restrict__ out, int ldout, int coloff, int Mtiles,
                       int nstg){
    int mt = blockIdx.x % Mtiles, nt = blockIdx.x / Mtiles;
    int lane = threadIdx.x & 63;
    int ln = lane & 15, lq = lane >> 4;
    floatx4 acc = {0.f, 0.f, 0.f, 0.f};
    const float* ap = A + (size_t)(mt * 16 + ln) * 256 + lq * 8;
    const float* bp = Whr + (size_t)(lq * 8) * 768 + nt * 16 + ln;
    for (int p0 = 0; p0 < 256; p0 += 32){
        short8 af, bf;
        #pragma unroll
        for (int j = 0; j < 8; ++j) af[j] = f2bf(ap[p0 + j]);
        #pragma unroll
        for (int j = 0; j < 8; ++j) bf[j] = f2bf(bp[(size_t)(p0 + j) * 768]);
        acc = __builtin_amdgcn_mfma_f32_16x16x32_bf16(af, bf, acc, 0, 0, 0);
    }
    #pragma unroll
    for (int r = 0; r < 4; ++r){
        int row = mt * 16 + lq * 4 + r, col = nt * 16 + ln;
        int k = coloff + col;
        if (nstg){
            int gg = row / 768, jj = row % 768;
            int ct = jj / 48, rr = jj % 48, ntB = rr / 16, lnB = rr % 16;
            int s = k >> 5, lqk = (k >> 3) & 3, e = k & 7;
            size_t off = ((((size_t)ct * nstg + s) * 4 + gg) * 3 + ntB) * 512
                       + (size_t)(lqk * 16 + lnB) * 8 + e;
            out[off] = f2bf(acc[r]);
        } else {
            out[(size_t)row * ldout + k] = f2bf(acc[r]);
        }
    }
}

// ---------------- per-wavefront step kernel: B in registers, A via DMA ------
// 480 blocks x 256 thr (2 blocks/CU, LDS 25KB). layer=bid%3, r2=bid/3:
// mt=r2>>4 (64 rows), ct=r2&15 (48 H-dims). Wave wg = gate wg.
// B: packed -> per-wave contiguous 1KB fragments, loaded DIRECTLY to VGPRs
//   (asm global_load_dwordx4, 3-slot register ring; slot k consumed at phase
//   k, reloaded with stage s0+3+k right after its MFMAs). No LDS round-trip.
// A: hidden chunk-major -> gll into 64x12-unit rotate-swizzled double buffer.
// Steady ledger (per wave, in-order): entering chunk = 9 [B+0,B+1,B+2];
//   +A(3)=12; ph0 VMW(9) [retires B+0]; ph1 VMW(9); ph2 VMW(9); end VMW(6)
//   [retires A]; exit 9. sched_barrier(0) after each VMW pins MFMA below it.
__global__ __launch_bounds__(256, 2) void k_step(const float* __restrict__ x,
        const short* __restrict__ B0, const short* __restrict__ B1,
        const short* __restrict__ B2, const float* __restrict__ bias,
        short* __restrict__ hidden, float* __restrict__ c, int w){
    __shared__ __align__(16) char smem[25088];      // sAr (24,576) / sEx (25,088)
    short* sAr = (short*)smem;                      // [2][64 rows x 12 units]
    float* sEx = (float*)smem;                      // overlay [4][32][49] fp32

    const int tid = threadIdx.x, lane = tid & 63, wg = tid >> 6;
    const int bid = blockIdx.x;
    const int layer = bid % 3;
    const int t = w - layer;
    if (t < 0 || t >= Tn) return;
    const int r2 = bid / 3;
    const int mt = r2 >> 4, ct = r2 & 15;
    const int m0 = mt * 64, j0 = ct * 48;
    const short* Bl = (layer == 0) ? B0 : (layer == 1) ? B1 : B2;
    const int NSTG = (layer == 0) ? 27 : 48;
    const int ln = lane & 15, lq = lane >> 4;
    const int rr = tid >> 2;
    const int pp = (w + 1) & 1;

    // per-lane packed-B base; stage/wg add a uniform offset
    const short* bglane = Bl + (size_t)lane * 8;
    const int ctb = ct * NSTG;

    // A DMA lane mapping (within a contiguous 12KB chunk block)
    int aoffA[3];
    #pragma unroll
    for (int j = 0; j < 3; ++j){
        int u = (wg * 3 + j) * 64 + lane;
        int row = u / 12, kcp = u % 12;
        int kcg = kcp - (row % 12); if (kcg < 0) kcg += 12;
        aoffA[j] = row * 96 + kcg * 8;
    }
    int prem[4];
    #pragma unroll
    for (int m4 = 0; m4 < 4; ++m4) prem[m4] = (m4 * 16 + ln) % 12;

    const short* srcA = (layer == 0) ? hidden + (size_t)pp * Bn * Hn
                       : hidden + (size_t)((layer - 1) * 2 + pp) * Bn * Hn;
    const short* srcH = hidden + (size_t)(layer * 2 + pp) * Bn * Hn;

    short8 bfr[3][3];   // register B ring [slot][nt] — slot always literal

#define LOADB(s_, slot_)                                                        \
    {                                                                           \
        const short* p_ = bglane + (size_t)(((ctb) + (s_)) * 12 + wg * 3) * 512;\
        asm volatile("global_load_dwordx4 %0, %1, off"                          \
                     : "=v"(bfr[slot_][0]) : "v"(p_) : "memory");               \
        asm volatile("global_load_dwordx4 %0, %1, off offset:1024"              \
                     : "=v"(bfr[slot_][1]) : "v"(p_) : "memory");               \
        asm volatile("global_load_dwordx4 %0, %1, off offset:2048"              \
                     : "=v"(bfr[slot_][2]) : "v"(p_) : "memory");               \
    }

    auto issueA = [&](int chn){
        const short* src; int chg;
        if (layer == 0 || chn < 8){ src = srcA; chg = chn; }
        else { src = srcH; chg = chn - 8; }
        const short* gb = src + (size_t)(mt * 8 + chg) * 6144;
        #pragma unroll
        for (int j = 0; j < 3; ++j)
            gll(gb + aoffA[j], &sAr[(chn & 1) * 6144 + (wg * 3 + j) * 512]);
    };

    floatx4 acc[4][3];
    #pragma unroll
    for (int nt = 0; nt < 3; ++nt){
        float bv = bias[layer * G4H + wg * Hn + j0 + nt * 16 + ln];
        #pragma unroll
        for (int m4 = 0; m4 < 4; ++m4){
            acc[m4][nt][0] = bv; acc[m4][nt][1] = bv;
            acc[m4][nt][2] = bv; acc[m4][nt][3] = bv;
        }
    }

// phase k: VMW -> sched_barrier -> afr ds_read -> MFMA (bfr[k]) -> reissue slot k
#define PH(k_, WAITN, ISSUE)                                                    \
    {                                                                           \
        VMW(WAITN);                                                             \
        __builtin_amdgcn_sched_barrier(0);                                      \
        short8 afr[4];                                                          \
        const int ksl_ = (k_) * 4 + lq;                                         \
        _Pragma("unroll")                                                       \
        for (int m4 = 0; m4 < 4; ++m4){                                         \
            int idx = prem[m4] + ksl_; if (idx >= 12) idx -= 12;                \
            afr[m4] = *(const short8*)&sAr[abuf * 6144 + ((m4 * 16 + ln) * 12 + idx) * 8]; \
        }                                                                       \
        _Pragma("unroll")                                                       \
        for (int m4 = 0; m4 < 4; ++m4)                                          \
            _Pragma("unroll")                                                   \
            for (int nt = 0; nt < 3; ++nt)                                      \
                acc[m4][nt] = __builtin_amdgcn_mfma_f32_16x16x32_bf16(afr[m4], bfr[k_][nt], acc[m4][nt], 0, 0, 0); \
        ISSUE;                                                                  \
    }

    // prologue: A(0) [3 gll], B stages 0-2 -> slots 0-2 [9]; VMW(9) retires A.
    issueA(0);
    LOADB(0, 0); LOADB(1, 1); LOADB(2, 2);
    VMW(9);
    __builtin_amdgcn_s_barrier();

    const int NST = (layer == 0) ? 7 : 15;   // steady chunks
    for (int ch = 0; ch < NST; ++ch){
        const int s0 = 3 * ch;
        const int abuf = ch & 1;
        issueA(ch + 1);
        PH(0, 9, LOADB(s0 + 3, 0));
        PH(1, 9, LOADB(s0 + 4, 1));
        PH(2, 9, LOADB(s0 + 5, 2));
        VMW(6);                      // retires A(ch+1)
        __builtin_amdgcn_s_barrier();
    }
    if (layer == 0){
        // chunk 7 (abuf=1): no A-issue (chunk 8 is x); issue B24-26
        {
            const int abuf = 1;
            PH(0, 6, LOADB(24, 0));
            PH(1, 6, LOADB(25, 1));
            PH(2, 6, LOADB(26, 2));
            __builtin_amdgcn_s_barrier();
        }
        // x-insert into A buf 0 with rotate layout
        {
            const float* xr = x + ((size_t)(m0 + rr) * Tn + t) * Fn;
            int q3 = (tid & 3) * 3;
            #pragma unroll
            for (int ii = 0; ii < 3; ++ii){
                int kcg = q3 + ii;          // global chunk 0..11
                int f = kcg * 8;
                short8 v = {0,0,0,0,0,0,0,0};
                if (f < Fn){
                    float4 a = *(const float4*)(xr + f);
                    float4 b = *(const float4*)(xr + f + 4);
                    v[0]=f2bf(a.x); v[1]=f2bf(a.y); v[2]=f2bf(a.z); v[3]=f2bf(a.w);
                    v[4]=f2bf(b.x); v[5]=f2bf(b.y); v[6]=f2bf(b.z); v[7]=f2bf(b.w);
                }
                int kcp = kcg + (rr % 12); if (kcp >= 12) kcp -= 12;
                *(short8*)&sAr[(rr * 12 + kcp) * 8] = v;
            }
            LGKM0;
            __builtin_amdgcn_s_barrier();
        }
        // chunk 8 (abuf=0): tail, entering [B24,B25,B26]=9
        {
            const int abuf = 0;
            PH(0, 6, (void)0);
            PH(1, 3, (void)0);
            PH(2, 0, (void)0);
            __builtin_amdgcn_s_barrier();
        }
    } else {
        // chunk 15 (abuf=1): tail, entering [B45,B46,B47]=9 (A15 retired)
        {
            const int abuf = 1;
            PH(0, 6, (void)0);
            PH(1, 3, (void)0);
            PH(2, 0, (void)0);
            __builtin_amdgcn_s_barrier();
        }
    }
#undef PH
#undef LOADB

    // ---- epilogue: 2-phase gate exchange (sEx overlays sAr; all reads done) ----
    #pragma unroll
    for (int p = 0; p < 2; ++p){
        if (p) __syncthreads();
        #pragma unroll
        for (int mm = 0; mm < 2; ++mm){
            int m4 = p * 2 + mm;
            #pragma unroll
            for (int nt = 0; nt < 3; ++nt)
                #pragma unroll
                for (int r = 0; r < 4; ++r)
                    sEx[(wg * 32 + mm * 16 + lq * 4 + r) * 49 + nt * 16 + ln] = acc[m4][nt][r];
        }
        __syncthreads();
        {
            int r32 = tid >> 3, cbp = (tid & 7) * 6;
            int row = p * 32 + r32;
            float* cp = c + ((size_t)layer * Bn + (m0 + row)) * Hn + j0 + cbp;
            short hb[6];
            #pragma unroll
            for (int ii = 0; ii < 6; ++ii){
                int cc_ = cbp + ii;
                float gi = sEx[(0 * 32 + r32) * 49 + cc_];
                float gf = sEx[(1 * 32 + r32) * 49 + cc_];
                float gg = sEx[(2 * 32 + r32) * 49 + cc_];
                float go = sEx[(3 * 32 + r32) * 49 + cc_];
                float cv = sigm(gf) * cp[ii] + sigm(gi) * tanh_(gg);
                cp[ii] = cv;
                hb[ii] = f2bf(sigm(go) * tanh_(cv));
            }
            // chunk-major h write: chunk ct>>1, col (ct&1)*48 + cbp
            short* hbase = hidden + (size_t)(layer * 2 + (w & 1)) * Bn * Hn;
            short* hp = hbase + ((size_t)((mt * 8 + (ct >> 1)) * 64 + row) * 96
                                 + (ct & 1) * 48 + cbp);
            #pragma unroll
            for (int q = 0; q < 3; ++q){
                unsigned v = (unsigned)(unsigned short)hb[q * 2] |
                             ((unsigned)(unsigned short)hb[q * 2 + 1] << 16);
                *(unsigned*)&hp[q * 2] = v;
            }
        }
    }
}

// ---------------- final: emb = normalize(relu(hidden2_last @ Wf^T + b)) -----
__global__ void k_final(const short* __restrict__ h2, const short* __restrict__ Wf,
                        const float* __restrict__ blin, float* __restrict__ out){
    __shared__ __align__(16) short sH[768];
    __shared__ float sW[4];
    int b = blockIdx.x, e = threadIdx.x;
    if (e < 96){
        int mtb = b >> 6, rowb = b & 63;
        *(short8*)&sH[e * 8] = *(const short8*)
            &h2[((size_t)(mtb * 8 + e / 12) * 64 + rowb) * 96 + (e % 12) * 8];
    }
    __syncthreads();
    float acc = blin[e];
    const short* wr = Wf + (size_t)e * 768;
    for (int j = 0; j < 768; j += 8){
        short8 hv = *(const short8*)&sH[j];
        short8 wv = *(const short8*)&wr[j];
        #pragma unroll
        for (int k = 0; k < 8; ++k) acc += bf2f(hv[k]) * bf2f(wv[k]);
    }
    float v = fmaxf(acc, 0.f);
    float s = v * v;
    #pragma unroll
    for (int off = 32; off >= 1; off >>= 1) s += __shfl_down(s, off);
    if ((e & 63) == 0) sW[e >> 6] = s;
    __syncthreads();
    float tot = sW[0] + sW[1] + sW[2] + sW[3];
    float scale = 1.f / fmaxf(sqrtf(tot), 1e-12f);
    out[(size_t)b * 256 + e] = v * scale;
}

// ---------------- host launcher ---------------------------------------------
extern "C" void kernel_launch(void* const* d_in, const int* in_sizes, int n_in,
                              void* d_out, int out_size, void* d_ws, size_t ws_size,
                              hipStream_t stream){
    const float* x    = (const float*)d_in[0];
    const float* Wih0 = (const float*)d_in[1];
    const float* Whh0 = (const float*)d_in[2];
    const float* bi0  = (const float*)d_in[3];
    const float* bh0  = (const float*)d_in[4];
    const float* Whr0 = (const float*)d_in[5];
    const float* Wih1 = (const float*)d_in[6];
    const float* Whh1 = (const float*)d_in[7];
    const float* bi1  = (const float*)d_in[8];
    const float* bh1  = (const float*)d_in[9];
    const float* Whr1 = (const float*)d_in[10];
    const float* Wih2 = (const float*)d_in[11];
    const float* Whh2 = (const float*)d_in[12];
    const float* bi2  = (const float*)d_in[13];
    const float* bh2  = (const float*)d_in[14];
    const float* Whr2 = (const float*)d_in[15];
    const float* Wlin = (const float*)d_in[16];
    const float* blin = (const float*)d_in[17];

    char* wp = (char*)d_ws;
    size_t off = 0;
    auto alloc = [&](size_t bytes) -> char* {
        char* p = wp + off; off += (bytes + 255) & ~(size_t)255; return p;
    };
    short* B0   = (short*)alloc((size_t)G4H * 864 * 2);
    short* B1   = (short*)alloc((size_t)G4H * 1536 * 2);
    short* B2   = (short*)alloc((size_t)G4H * 1536 * 2);
    short* Wf   = (short*)alloc((size_t)256 * 768 * 2);
    float* bias = (float*)alloc((size_t)3 * G4H * 4);
    short* hid  = (short*)alloc((size_t)3 * 2 * Bn * Hn * 2);
    float* cst  = (float*)alloc((size_t)3 * Bn * Hn * 4);

    hipLaunchKernelGGL(k_prep, dim3(1188), dim3(256), 0, stream,
                       Wih0, bi0, bh0, bi1, bh1, bi2, bh2, B0, bias);
    hipLaunchKernelGGL(k_init, dim3(1024), dim3(256), 0, stream, hid, cst);
    // folds (packed): R_l = Whh_l @ Whr_l ; U_l = Wih_l @ Whr_{l-1}
    hipLaunchKernelGGL(k_fold, dim3(192 * 48), dim3(64), 0, stream, Whh0, Whr0, B0, 0, 0,   192, 27);
    hipLaunchKernelGGL(k_fold, dim3(192 * 48), dim3(64), 0, stream, Wih1, Whr0, B1, 0, 0,   192, 48);
    hipLaunchKernelGGL(k_fold, dim3(192 * 48), dim3(64), 0, stream, Whh1, Whr1, B1, 0, 768, 192, 48);
    hipLaunchKernelGGL(k_fold, dim3(192 * 48), dim3(64), 0, stream, Wih2, Whr1, B2, 0, 0,   192, 48);
    hipLaunchKernelGGL(k_fold, dim3(192 * 48), dim3(64), 0, stream, Whh2, Whr2, B2, 0, 768, 192, 48);
    // Wf stays linear (k_final reads row-major)
    hipLaunchKernelGGL(k_fold, dim3(16 * 48), dim3(64), 0, stream, Wlin, Whr2, Wf, 768, 0, 16, 0);

    for (int w = 0; w < 162; ++w)
        hipLaunchKernelGGL(k_step, dim3(NBLK), dim3(256), 0, stream,
                           x, B0, B1, B2, bias, hid, cst, w);

    const short* h2 = hid + (size_t)5 * Bn * Hn;   // layer 2, parity 1, chunk-major
    hipLaunchKernelGGL(k_final, dim3(Bn), dim3(256), 0, stream, h2, Wf, blin, (float*)d_out);
}